// Round 1
// baseline (339.890 us; speedup 1.0000x reference)
//
#include <hip/hip_runtime.h>

// Problem constants (B=1)
#define SS 256
#define DD 512
#define NN 8
#define HH 64

// ---------------------------------------------------------------------------
// Kernel A: projections.  For each head n compute 5 [S x H] tensors:
//   K1 = x@W_K1 + b_K1,  K2 = x@W_K2 + b_K2,  Qs = (x@W_Q + b_Q)/64,
//   VA = x@W_V12[:, :D], VB = x@W_V12[:, D:]
// grid = 5 mats * 8 n * 8 ptiles = 320 blocks, 256 threads.
// Wave w of a block handles rows p0..p0+7 (wave-uniform -> scalar x loads);
// lane = h (coalesced W loads, 256B per instruction).
// ---------------------------------------------------------------------------
__global__ __launch_bounds__(256) void proj_kernel(
    const float* __restrict__ x,
    const float* __restrict__ WK1, const float* __restrict__ WK2,
    const float* __restrict__ WQ,  const float* __restrict__ WV12,
    const float* __restrict__ bK1, const float* __restrict__ bK2,
    const float* __restrict__ bQ,
    float* __restrict__ K1b, float* __restrict__ K2b, float* __restrict__ Qb,
    float* __restrict__ VAb, float* __restrict__ VBb)
{
    const int blk = blockIdx.x;
    const int pt = blk & 7;         // 8 p-tiles of 32 rows
    const int n  = (blk >> 3) & 7;  // head
    const int m  = blk >> 6;        // which matrix (0..4)
    const int h  = threadIdx.x & 63;
    int p0 = pt * 32 + (threadIdx.x >> 6) * 8;
    p0 = __builtin_amdgcn_readfirstlane(p0);  // wave-uniform: enable s_load for x

    const float* W;
    float* outb;
    if (m == 0)      { W = WK1  + n * DD * HH;            outb = K1b; }
    else if (m == 1) { W = WK2  + n * DD * HH;            outb = K2b; }
    else if (m == 2) { W = WQ   + n * DD * HH;            outb = Qb;  }
    else if (m == 3) { W = WV12 + n * 2 * DD * HH;        outb = VAb; }
    else             { W = WV12 + n * 2 * DD * HH + DD*HH; outb = VBb; }

    float acc[8] = {0.f,0.f,0.f,0.f,0.f,0.f,0.f,0.f};
    for (int d = 0; d < DD; d += 4) {
        const float w0 = W[(d + 0) * HH + h];
        const float w1 = W[(d + 1) * HH + h];
        const float w2 = W[(d + 2) * HH + h];
        const float w3 = W[(d + 3) * HH + h];
        #pragma unroll
        for (int r = 0; r < 8; ++r) {
            const float4 xv = *(const float4*)(x + (p0 + r) * DD + d);
            acc[r] = fmaf(xv.x, w0, acc[r]);
            acc[r] = fmaf(xv.y, w1, acc[r]);
            acc[r] = fmaf(xv.z, w2, acc[r]);
            acc[r] = fmaf(xv.w, w3, acc[r]);
        }
    }
    float bv = 0.f;
    if (m == 0)      bv = bK1[n * HH + h];
    else if (m == 1) bv = bK2[n * HH + h];
    else if (m == 2) bv = bQ[n * HH + h];
    const float scale = (m == 2) ? (1.0f / 64.0f) : 1.0f;  // fold 1/H into Q
    #pragma unroll
    for (int r = 0; r < 8; ++r)
        outb[(n * SS + p0 + r) * HH + h] = (acc[r] + bv) * scale;
}

// ---------------------------------------------------------------------------
// Kernel B: per (n, q) block computes the softmax marginals over valid pairs
// {s < t < q} and then z[q,n,:] = sum_s a_s VA[s] + sum_t c_t VB[t] + b_V12.
// Masked entries underflow to exactly 0 in the reference (exp(-1e6/64-m)=0),
// so single-pass exp with implicit max=0 is exact.  q<2: all-masked row ->
// uniform softmax -> a = c = 1/256.
// Thread owns s = tid; k2[t] rows are block-uniform loads (s_load).
// Big-q blocks are dispatched first (load balance).
// ---------------------------------------------------------------------------
__global__ __launch_bounds__(256) void attn_kernel(
    const float* __restrict__ K1b, const float* __restrict__ K2b,
    const float* __restrict__ Qb,  const float* __restrict__ VAb,
    const float* __restrict__ VBb, const float* __restrict__ bV12,
    float* __restrict__ zb)
{
    const int n = blockIdx.x & 7;
    const int q = (SS - 1) - (int)(blockIdx.x >> 3);  // big q first
    const int tid  = threadIdx.x;
    const int lane = tid & 63;
    const int wid  = tid >> 6;
    const int s    = tid;

    __shared__ float c_lds[SS];
    __shared__ float red[4];
    __shared__ float a_lds[SS];
    __shared__ float zred[4][HH];

    c_lds[tid] = 0.f;

    // A[h] = k1[n,s,h] * qs[n,q,h]   (qs already has bias and /64 folded in)
    float A[HH];
    const float* K1row = K1b + (n * SS + s) * HH;
    const float* Qrow  = Qb  + (n * SS + q) * HH;   // block-uniform
    #pragma unroll
    for (int h = 0; h < HH; h += 4) {
        const float4 kv = *(const float4*)(K1row + h);
        const float4 qv = *(const float4*)(Qrow + h);
        A[h + 0] = kv.x * qv.x;
        A[h + 1] = kv.y * qv.y;
        A[h + 2] = kv.z * qv.z;
        A[h + 3] = kv.w * qv.w;
    }
    __syncthreads();

    float a_reg = 0.f;
    if (q >= 2) {
        for (int t = 1; t < q; ++t) {
            if ((wid << 6) < t) {          // wave has >=1 active lane
                float e = 0.f;
                if (s < t) {
                    const float* K2row = K2b + (n * SS + t) * HH;  // uniform
                    float sc = 0.f;
                    #pragma unroll
                    for (int h = 0; h < HH; h += 4) {
                        const float4 kv = *(const float4*)(K2row + h);
                        sc = fmaf(A[h + 0], kv.x, sc);
                        sc = fmaf(A[h + 1], kv.y, sc);
                        sc = fmaf(A[h + 2], kv.z, sc);
                        sc = fmaf(A[h + 3], kv.w, sc);
                    }
                    e = __expf(sc);
                    a_reg += e;            // marginal over t for own s
                }
                // wave-sum e -> c_t
                float es = e;
                #pragma unroll
                for (int off = 32; off >= 1; off >>= 1)
                    es += __shfl_xor(es, off, 64);
                if (lane == 0) atomicAdd(&c_lds[t], es);
            }
        }
    }
    __syncthreads();

    // Z = sum of all e  (== sum_s a_s)
    float zsum = a_reg;
    #pragma unroll
    for (int off = 32; off >= 1; off >>= 1)
        zsum += __shfl_xor(zsum, off, 64);
    if (lane == 0) red[wid] = zsum;
    __syncthreads();

    if (q >= 2) {
        const float Z = red[0] + red[1] + red[2] + red[3];
        const float inv = 1.0f / Z;
        a_lds[tid] = a_reg * inv;
        c_lds[tid] *= inv;
    } else {
        // fully-masked row: softmax uniform over all 65536 pairs
        a_lds[tid] = 1.0f / 256.0f;
        c_lds[tid] = 1.0f / 256.0f;
    }
    __syncthreads();

    // z[h] = sum_s a_s VA[s,h] + sum_t c_t VB[t,h] + b_V12
    const int h = lane;
    const int g = wid;                      // s-range [g*64, g*64+64)
    float acc = 0.f;
    for (int i = 0; i < 64; ++i) {
        const int si = (g << 6) + i;
        acc = fmaf(a_lds[si], VAb[(n * SS + si) * HH + h], acc);
        acc = fmaf(c_lds[si], VBb[(n * SS + si) * HH + h], acc);
    }
    zred[g][h] = acc;
    __syncthreads();
    if (wid == 0) {
        const float zv = zred[0][h] + zred[1][h] + zred[2][h] + zred[3][h]
                       + bV12[n * HH + h];
        zb[(q * NN + n) * HH + h] = zv;     // layout [q][(n,h)] for epilogue GEMM
    }
}

// ---------------------------------------------------------------------------
// Kernel C: out[q,d] = sum_{k=(n,h)} z[q,k] * W_O[k,d] + b_O[d]
// grid = 64 blocks (4 q-rows each), 256 threads (2 d-columns each).
// z reads are block-uniform -> s_load; W_O reads coalesced over d.
// ---------------------------------------------------------------------------
__global__ __launch_bounds__(256) void out_kernel(
    const float* __restrict__ zb, const float* __restrict__ WO,
    const float* __restrict__ bO, float* __restrict__ out)
{
    const int q0 = blockIdx.x * 4;
    const int t  = threadIdx.x;
    float acc0[4] = {0.f,0.f,0.f,0.f};
    float acc1[4] = {0.f,0.f,0.f,0.f};
    for (int k = 0; k < DD; ++k) {
        const float w0 = WO[k * DD + t];
        const float w1 = WO[k * DD + t + 256];
        #pragma unroll
        for (int r = 0; r < 4; ++r) {
            const float zv = zb[(q0 + r) * DD + k];  // uniform -> s_load
            acc0[r] = fmaf(zv, w0, acc0[r]);
            acc1[r] = fmaf(zv, w1, acc1[r]);
        }
    }
    #pragma unroll
    for (int r = 0; r < 4; ++r) {
        out[(q0 + r) * DD + t]       = acc0[r] + bO[t];
        out[(q0 + r) * DD + t + 256] = acc1[r] + bO[t + 256];
    }
}

// ---------------------------------------------------------------------------
extern "C" void kernel_launch(void* const* d_in, const int* in_sizes, int n_in,
                              void* d_out, int out_size, void* d_ws, size_t ws_size,
                              hipStream_t stream)
{
    const float* x    = (const float*)d_in[0];
    const float* WK1  = (const float*)d_in[1];
    const float* WK2  = (const float*)d_in[2];
    const float* WQ   = (const float*)d_in[3];
    const float* WV12 = (const float*)d_in[4];
    const float* WO   = (const float*)d_in[5];
    const float* bK1  = (const float*)d_in[6];
    const float* bK2  = (const float*)d_in[7];
    const float* bQ   = (const float*)d_in[8];
    const float* bV12 = (const float*)d_in[9];
    const float* bO   = (const float*)d_in[10];
    float* out = (float*)d_out;

    float* ws  = (float*)d_ws;
    const int T = NN * SS * HH;  // 131072 floats per projected tensor
    float* K1b = ws + 0 * T;
    float* K2b = ws + 1 * T;
    float* Qb  = ws + 2 * T;
    float* VAb = ws + 3 * T;
    float* VBb = ws + 4 * T;
    float* zb  = ws + 5 * T;

    proj_kernel<<<320, 256, 0, stream>>>(x, WK1, WK2, WQ, WV12,
                                         bK1, bK2, bQ,
                                         K1b, K2b, Qb, VAb, VBb);
    attn_kernel<<<2048, 256, 0, stream>>>(K1b, K2b, Qb, VAb, VBb, bV12, zb);
    out_kernel<<<64, 256, 0, stream>>>(zb, WO, bO, out);
}

// Round 2
// 145.586 us; speedup vs baseline: 2.3346x; 2.3346x over previous
//
#include <hip/hip_runtime.h>

// Problem constants (B=1)
#define SS 256
#define DD 512
#define NN 8
#define HH 64

typedef __bf16 bf16x8 __attribute__((ext_vector_type(8)));
typedef __bf16 bf16x4 __attribute__((ext_vector_type(4)));
typedef float  floatx4 __attribute__((ext_vector_type(4)));

// ---------------------------------------------------------------------------
// Kernel A: projections.  K1 = x@W_K1 + b_K1, K2 = x@W_K2 + b_K2,
// Qs = (x@W_Q + b_Q)/64, VA = x@W_V12[:, :D], VB = x@W_V12[:, D:]   (all f32)
// grid = 5 mats * 8 n * 32 ptiles = 1280 blocks, 256 threads.
// Wave handles 2 rows (wave-uniform p0 -> s_load for x); lane = h (coalesced W).
// ---------------------------------------------------------------------------
__global__ __launch_bounds__(256) void proj_kernel(
    const float* __restrict__ x,
    const float* __restrict__ WK1, const float* __restrict__ WK2,
    const float* __restrict__ WQ,  const float* __restrict__ WV12,
    const float* __restrict__ bK1, const float* __restrict__ bK2,
    const float* __restrict__ bQ,
    float* __restrict__ K1b, float* __restrict__ K2b, float* __restrict__ Qb,
    float* __restrict__ VAb, float* __restrict__ VBb)
{
    const int blk = blockIdx.x;
    const int pt = blk & 31;        // 32 p-tiles of 8 rows
    const int n  = (blk >> 5) & 7;  // head
    const int m  = blk >> 8;        // which matrix (0..4)
    const int h  = threadIdx.x & 63;
    int p0 = pt * 8 + (threadIdx.x >> 6) * 2;
    p0 = __builtin_amdgcn_readfirstlane(p0);  // wave-uniform rows -> s_load x

    const float* W;
    float* outb;
    if (m == 0)      { W = WK1  + n * DD * HH;             outb = K1b; }
    else if (m == 1) { W = WK2  + n * DD * HH;             outb = K2b; }
    else if (m == 2) { W = WQ   + n * DD * HH;             outb = Qb;  }
    else if (m == 3) { W = WV12 + n * 2 * DD * HH;         outb = VAb; }
    else             { W = WV12 + n * 2 * DD * HH + DD*HH; outb = VBb; }

    float acc0 = 0.f, acc1 = 0.f;
    for (int d = 0; d < DD; d += 4) {
        const float w0 = W[(d + 0) * HH + h];
        const float w1 = W[(d + 1) * HH + h];
        const float w2 = W[(d + 2) * HH + h];
        const float w3 = W[(d + 3) * HH + h];
        const float4 x0 = *(const float4*)(x + (p0 + 0) * DD + d);
        const float4 x1 = *(const float4*)(x + (p0 + 1) * DD + d);
        acc0 = fmaf(x0.x, w0, acc0); acc0 = fmaf(x0.y, w1, acc0);
        acc0 = fmaf(x0.z, w2, acc0); acc0 = fmaf(x0.w, w3, acc0);
        acc1 = fmaf(x1.x, w0, acc1); acc1 = fmaf(x1.y, w1, acc1);
        acc1 = fmaf(x1.z, w2, acc1); acc1 = fmaf(x1.w, w3, acc1);
    }
    float bv = 0.f;
    if (m == 0)      bv = bK1[n * HH + h];
    else if (m == 1) bv = bK2[n * HH + h];
    else if (m == 2) bv = bQ[n * HH + h];
    const float scale = (m == 2) ? (1.0f / 64.0f) : 1.0f;  // fold 1/H into Q
    outb[(n * SS + p0 + 0) * HH + h] = (acc0 + bv) * scale;
    outb[(n * SS + p0 + 1) * HH + h] = (acc1 + bv) * scale;
}

// ---------------------------------------------------------------------------
// Kernel B: per (n, q) block.  MFMA 16x16x32 bf16 computes the score tiles
// S[s,t] = sum_h (k1[s,h]*qs[q,h]) * k2[t,h]; e = exp(S) masked to {s<t<q};
// marginals a_s = sum_t e, c_t = sum_s e; then
// z[q,n,:] = (sum_s a_s VA[s] + sum_t c_t VB[t]) / Z + b_V12.
// Masked entries are exactly 0 in the reference (exp underflow), so excluding
// them is exact; q<2 rows are fully masked -> uniform 1/256 marginals.
// LDS: K2 as bf16, XOR-swizzled 16B chunks (conflict-free ds_read_b128).
// A-fragments built in-register from global k1 (reused over all t of a strip).
// ---------------------------------------------------------------------------
__global__ __launch_bounds__(256) void attn_kernel(
    const float* __restrict__ K1b, const float* __restrict__ K2b,
    const float* __restrict__ Qb,  const float* __restrict__ VAb,
    const float* __restrict__ VBb, const float* __restrict__ bV12,
    float* __restrict__ zb)
{
    const int n = blockIdx.x & 7;
    const int q = (SS - 1) - (int)(blockIdx.x >> 3);  // big q first
    const int tid  = threadIdx.x;
    const int lane = tid & 63;
    const int wid  = tid >> 6;
    const int r15  = lane & 15;   // MFMA free-dim index
    const int quad = lane >> 4;   // MFMA k-group / row-group

    __shared__ __bf16 K2sh[SS * HH];   // 32 KB, xor-swizzled 16B chunks
    __shared__ float qsh[HH];
    __shared__ float a_lds[SS];
    __shared__ float c_lds[SS];
    __shared__ float zred[4][HH];
    __shared__ float red[4];

    // ---- stage K2 (f32 -> bf16, swizzled) + qs -------------------------------
    {
        const int c4 = tid & 15;          // 4-float chunk within row
        const int c8 = c4 >> 1;           // 16B chunk index (0..7)
        const int half = (c4 & 1) * 4;    // low/high half of 16B chunk
        for (int it = 0; it < 16; ++it) {
            const int row = (tid >> 4) + it * 16;
            const float4 kv = *(const float4*)(K2b + ((n << 8) + row) * HH + c4 * 4);
            bf16x4 v;
            v[0] = (__bf16)kv.x; v[1] = (__bf16)kv.y;
            v[2] = (__bf16)kv.z; v[3] = (__bf16)kv.w;
            *(bf16x4*)&K2sh[row * HH + ((c8 ^ (row & 7)) << 3) + half] = v;
        }
        if (tid < 16) {
            const float4 qv = ((const float4*)(Qb + ((n << 8) + q) * HH))[tid];
            *(float4*)&qsh[tid * 4] = qv;
        }
        if (q >= 2) { a_lds[tid] = 0.f; c_lds[tid] = 0.f; }
        else        { a_lds[tid] = 1.0f / SS; c_lds[tid] = 1.0f / SS; }
    }
    __syncthreads();

    // ---- score tiles ---------------------------------------------------------
    if (q >= 2) {
        // strips {w, 7-w, 8+w, 15-w}: per-wave work is constant (balance)
        #pragma unroll
        for (int j = 0; j < 4; ++j) {
            int strip;
            if (j == 0) strip = wid;
            else if (j == 1) strip = 7 - wid;
            else if (j == 2) strip = 8 + wid;
            else strip = 15 - wid;
            const int s0 = strip << 4;
            if (s0 > q - 2) continue;

            // A-fragments for K=64 (two K=32 MFMAs), built from global k1*qs
            const float* k1p = K1b + ((n << 8) + s0 + r15) * HH;
            const float4 ka = *(const float4*)(k1p + quad * 8);
            const float4 kb = *(const float4*)(k1p + quad * 8 + 4);
            const float4 kc = *(const float4*)(k1p + 32 + quad * 8);
            const float4 kd = *(const float4*)(k1p + 32 + quad * 8 + 4);
            const float4 qa = *(const float4*)&qsh[quad * 8];
            const float4 qb_ = *(const float4*)&qsh[quad * 8 + 4];
            const float4 qc = *(const float4*)&qsh[32 + quad * 8];
            const float4 qd = *(const float4*)&qsh[32 + quad * 8 + 4];
            bf16x8 a0, a1;
            a0[0] = (__bf16)(ka.x * qa.x); a0[1] = (__bf16)(ka.y * qa.y);
            a0[2] = (__bf16)(ka.z * qa.z); a0[3] = (__bf16)(ka.w * qa.w);
            a0[4] = (__bf16)(kb.x * qb_.x); a0[5] = (__bf16)(kb.y * qb_.y);
            a0[6] = (__bf16)(kb.z * qb_.z); a0[7] = (__bf16)(kb.w * qb_.w);
            a1[0] = (__bf16)(kc.x * qc.x); a1[1] = (__bf16)(kc.y * qc.y);
            a1[2] = (__bf16)(kc.z * qc.z); a1[3] = (__bf16)(kc.w * qc.w);
            a1[4] = (__bf16)(kd.x * qd.x); a1[5] = (__bf16)(kd.y * qd.y);
            a1[6] = (__bf16)(kd.z * qd.z); a1[7] = (__bf16)(kd.w * qd.w);

            float rowAcc[4] = {0.f, 0.f, 0.f, 0.f};
            const int swz = (r15 & 7);
            for (int t0 = s0; t0 < q; t0 += 16) {
                const __bf16* K2row = &K2sh[(t0 + r15) * HH];
                const bf16x8 b0 = *(const bf16x8*)&K2row[((quad    ) ^ swz) << 3];
                const bf16x8 b1 = *(const bf16x8*)&K2row[((quad + 4) ^ swz) << 3];
                floatx4 C = {0.f, 0.f, 0.f, 0.f};
                C = __builtin_amdgcn_mfma_f32_16x16x32_bf16(a0, b0, C, 0, 0, 0);
                C = __builtin_amdgcn_mfma_f32_16x16x32_bf16(a1, b1, C, 0, 0, 0);

                float e[4];
                const bool interior = (t0 >= s0 + 16) && (t0 + 16 <= q);
                if (interior) {
                    #pragma unroll
                    for (int i = 0; i < 4; ++i) e[i] = __expf(C[i]);
                } else {
                    const int t = t0 + r15;
                    #pragma unroll
                    for (int i = 0; i < 4; ++i) {
                        const int s = s0 + quad * 4 + i;
                        const bool valid = (s < t) && (t < q);
                        e[i] = valid ? __expf(C[i]) : 0.f;
                    }
                }
                #pragma unroll
                for (int i = 0; i < 4; ++i) rowAcc[i] += e[i];

                // column (t) sums: lanes {r15, r15+16, r15+32, r15+48}
                float cs = (e[0] + e[1]) + (e[2] + e[3]);
                cs += __shfl_xor(cs, 16, 64);
                cs += __shfl_xor(cs, 32, 64);
                if (lane < 16) atomicAdd(&c_lds[t0 + r15], cs);
            }
            // row (s) sums: butterfly over the 16 column-lanes
            #pragma unroll
            for (int i = 0; i < 4; ++i) {
                rowAcc[i] += __shfl_xor(rowAcc[i], 1, 64);
                rowAcc[i] += __shfl_xor(rowAcc[i], 2, 64);
                rowAcc[i] += __shfl_xor(rowAcc[i], 4, 64);
                rowAcc[i] += __shfl_xor(rowAcc[i], 8, 64);
            }
            if (r15 == 0) {
                #pragma unroll
                for (int i = 0; i < 4; ++i)
                    a_lds[s0 + quad * 4 + i] = rowAcc[i];   // strip-exclusive rows
            }
        }
    }
    __syncthreads();

    // ---- Z = sum of all e ----------------------------------------------------
    float v = a_lds[tid];
    #pragma unroll
    for (int off = 32; off >= 1; off >>= 1) v += __shfl_xor(v, off, 64);
    if (lane == 0) red[wid] = v;
    __syncthreads();
    const float invZ = 1.0f / (red[0] + red[1] + red[2] + red[3]);  // q<2: Z=1

    // ---- z = (sum_s a_s VA[s] + sum_t c_t VB[t]) * invZ + b_V12 --------------
    {
        const int h = lane;
        const int g = wid;
        const float* VAp = VAb + ((n << 8) + (g << 6)) * HH + h;
        const float* VBp = VBb + ((n << 8) + (g << 6)) * HH + h;
        float acc = 0.f;
        for (int i = 0; i < 64; ++i) {
            const int si = (g << 6) + i;
            acc = fmaf(a_lds[si], VAp[i * HH], acc);
            acc = fmaf(c_lds[si], VBp[i * HH], acc);
        }
        zred[g][h] = acc;
    }
    __syncthreads();
    if (wid == 0) {
        const int h = lane;
        const float zv = (zred[0][h] + zred[1][h] + zred[2][h] + zred[3][h]) * invZ
                       + bV12[n * HH + h];
        zb[q * DD + n * HH + h] = zv;   // z row q = [n*64+h], matches W_O's k
    }
}

// ---------------------------------------------------------------------------
// Kernel C: out[q,d] = sum_k z[q,k] * W_O[k,d] + b_O[d]   (f32)
// grid = 64 q-tiles * 4 d-quarters = 256 blocks, 256 threads.
// Wave = (q-pair, k-half); z staged in LDS; float2 W loads; k-split partials
// combined through LDS.
// ---------------------------------------------------------------------------
__global__ __launch_bounds__(256) void out_kernel(
    const float* __restrict__ zb, const float* __restrict__ WO,
    const float* __restrict__ bO, float* __restrict__ out)
{
    const int q0 = (blockIdx.x >> 2) * 4;
    const int d0 = (blockIdx.x & 3) * 128;
    const int tid = threadIdx.x;
    const int lane = tid & 63;
    const int wid = tid >> 6;

    __shared__ float zsh[4][DD];      // 8 KB
    __shared__ float zpart[4][128];   // 2 KB

    for (int idx = tid; idx < 4 * DD; idx += 256) {
        const int r = idx >> 9, k = idx & 511;
        zsh[r][k] = zb[(q0 + r) * DD + k];
    }
    __syncthreads();

    const int qp = wid & 1;           // q-pair: rows {2qp, 2qp+1}
    const int kh = wid >> 1;          // k-half
    const int d = d0 + lane * 2;
    float2 acc0 = {0.f, 0.f}, acc1 = {0.f, 0.f};
    const int k0 = kh * 256;
    for (int k = k0; k < k0 + 256; k += 4) {
        #pragma unroll
        for (int u = 0; u < 4; ++u) {
            const float2 w = *(const float2*)(WO + (k + u) * DD + d);
            const float z0 = zsh[2 * qp + 0][k + u];
            const float z1 = zsh[2 * qp + 1][k + u];
            acc0.x = fmaf(z0, w.x, acc0.x); acc0.y = fmaf(z0, w.y, acc0.y);
            acc1.x = fmaf(z1, w.x, acc1.x); acc1.y = fmaf(z1, w.y, acc1.y);
        }
    }
    if (kh == 0) {
        *(float2*)&zpart[2 * qp + 0][lane * 2] = acc0;
        *(float2*)&zpart[2 * qp + 1][lane * 2] = acc1;
    }
    __syncthreads();
    if (kh == 1) {
        const float2 p0 = *(const float2*)&zpart[2 * qp + 0][lane * 2];
        const float2 p1 = *(const float2*)&zpart[2 * qp + 1][lane * 2];
        const float2 bv = *(const float2*)(bO + d);
        float2 o0, o1;
        o0.x = acc0.x + p0.x + bv.x; o0.y = acc0.y + p0.y + bv.y;
        o1.x = acc1.x + p1.x + bv.x; o1.y = acc1.y + p1.y + bv.y;
        *(float2*)(out + (q0 + 2 * qp + 0) * DD + d) = o0;
        *(float2*)(out + (q0 + 2 * qp + 1) * DD + d) = o1;
    }
}

// ---------------------------------------------------------------------------
extern "C" void kernel_launch(void* const* d_in, const int* in_sizes, int n_in,
                              void* d_out, int out_size, void* d_ws, size_t ws_size,
                              hipStream_t stream)
{
    const float* x    = (const float*)d_in[0];
    const float* WK1  = (const float*)d_in[1];
    const float* WK2  = (const float*)d_in[2];
    const float* WQ   = (const float*)d_in[3];
    const float* WV12 = (const float*)d_in[4];
    const float* WO   = (const float*)d_in[5];
    const float* bK1  = (const float*)d_in[6];
    const float* bK2  = (const float*)d_in[7];
    const float* bQ   = (const float*)d_in[8];
    const float* bV12 = (const float*)d_in[9];
    const float* bO   = (const float*)d_in[10];
    float* out = (float*)d_out;

    float* ws  = (float*)d_ws;
    const int T = NN * SS * HH;  // 131072 floats per projected tensor
    float* K1b = ws + 0 * T;
    float* K2b = ws + 1 * T;
    float* Qb  = ws + 2 * T;
    float* VAb = ws + 3 * T;
    float* VBb = ws + 4 * T;
    float* zb  = ws + 5 * T;

    proj_kernel<<<1280, 256, 0, stream>>>(x, WK1, WK2, WQ, WV12,
                                          bK1, bK2, bQ,
                                          K1b, K2b, Qb, VAb, VBb);
    attn_kernel<<<2048, 256, 0, stream>>>(K1b, K2b, Qb, VAb, VBb, bV12, zb);
    out_kernel<<<256, 256, 0, stream>>>(zb, WO, bO, out);
}

// Round 3
// 145.118 us; speedup vs baseline: 2.3422x; 1.0032x over previous
//
#include <hip/hip_runtime.h>

// Problem constants (B=1)
#define SS 256
#define DD 512
#define NN 8
#define HH 64

typedef __bf16 bf16x8 __attribute__((ext_vector_type(8)));
typedef __bf16 bf16x4 __attribute__((ext_vector_type(4)));
typedef float  floatx4 __attribute__((ext_vector_type(4)));

// ---------------------------------------------------------------------------
// Kernel A: projections.  K1 = x@W_K1 + b_K1, K2 = x@W_K2 + b_K2,
// Qs = (x@W_Q + b_Q)/64, VA = x@W_V12[:, :D], VB = x@W_V12[:, D:]   (all f32)
// grid = 5 mats * 8 n * 8 ptiles = 320 blocks, 512 threads (8 waves x 4 rows).
// One block reads its 512KB W-slice ONCE (waves share L1 lines) -> L2 traffic
// 184MB total vs 640MB before.  x rows via wave-uniform s_load.
// ---------------------------------------------------------------------------
__global__ __launch_bounds__(512) void proj_kernel(
    const float* __restrict__ x,
    const float* __restrict__ WK1, const float* __restrict__ WK2,
    const float* __restrict__ WQ,  const float* __restrict__ WV12,
    const float* __restrict__ bK1, const float* __restrict__ bK2,
    const float* __restrict__ bQ,
    float* __restrict__ K1b, float* __restrict__ K2b, float* __restrict__ Qb,
    float* __restrict__ VAb, float* __restrict__ VBb)
{
    const int blk = blockIdx.x;
    const int pt = blk & 7;         // 8 p-tiles of 32 rows
    const int n  = (blk >> 3) & 7;  // head
    const int m  = blk >> 6;        // which matrix (0..4)
    const int h  = threadIdx.x & 63;
    int p0 = pt * 32 + (threadIdx.x >> 6) * 4;   // wave w: rows p0..p0+3
    p0 = __builtin_amdgcn_readfirstlane(p0);     // wave-uniform -> s_load x

    const float* W;
    float* outb;
    if (m == 0)      { W = WK1  + n * DD * HH;             outb = K1b; }
    else if (m == 1) { W = WK2  + n * DD * HH;             outb = K2b; }
    else if (m == 2) { W = WQ   + n * DD * HH;             outb = Qb;  }
    else if (m == 3) { W = WV12 + n * 2 * DD * HH;         outb = VAb; }
    else             { W = WV12 + n * 2 * DD * HH + DD*HH; outb = VBb; }

    float acc[4] = {0.f, 0.f, 0.f, 0.f};
    for (int d = 0; d < DD; d += 8) {
        float w[8];
        #pragma unroll
        for (int j = 0; j < 8; ++j) w[j] = W[(d + j) * HH + h];
        #pragma unroll
        for (int r = 0; r < 4; ++r) {
            const float4 xa = *(const float4*)(x + (p0 + r) * DD + d);
            const float4 xb = *(const float4*)(x + (p0 + r) * DD + d + 4);
            acc[r] = fmaf(xa.x, w[0], acc[r]); acc[r] = fmaf(xa.y, w[1], acc[r]);
            acc[r] = fmaf(xa.z, w[2], acc[r]); acc[r] = fmaf(xa.w, w[3], acc[r]);
            acc[r] = fmaf(xb.x, w[4], acc[r]); acc[r] = fmaf(xb.y, w[5], acc[r]);
            acc[r] = fmaf(xb.z, w[6], acc[r]); acc[r] = fmaf(xb.w, w[7], acc[r]);
        }
    }
    float bv = 0.f;
    if (m == 0)      bv = bK1[n * HH + h];
    else if (m == 1) bv = bK2[n * HH + h];
    else if (m == 2) bv = bQ[n * HH + h];
    const float scale = (m == 2) ? (1.0f / 64.0f) : 1.0f;  // fold 1/H into Q
    #pragma unroll
    for (int r = 0; r < 4; ++r)
        outb[(n * SS + p0 + r) * HH + h] = (acc[r] + bv) * scale;
}

// ---------------------------------------------------------------------------
// Kernel B: block = (n, q-group of 4).  q-group {g, 127-g, 128+g, 255-g}
// (ascending; work spread across groups only 1.2:1).  K2 staged once (bf16,
// xor-swizzled), A-frags per (strip, q) from global k1 * LDS qs; per tile
// B-frags shared across the 4 q's.  Marginals a_s (register+butterfly) and
// c_t (LDS atomic) per q; masked entries are exactly 0 in the reference
// (exp underflow) so excluding them is exact; q<2 rows are fully masked ->
// preset uniform 1/256 (Z then sums to exactly 1.0, same normalize path).
// ---------------------------------------------------------------------------
__global__ __launch_bounds__(256, 3) void attn_kernel(
    const float* __restrict__ K1b, const float* __restrict__ K2b,
    const float* __restrict__ Qb,  const float* __restrict__ VAb,
    const float* __restrict__ VBb, const float* __restrict__ bV12,
    float* __restrict__ zb)
{
    const int n = blockIdx.x & 7;            // %8: same head -> same XCD L2
    const int g = (int)(blockIdx.x >> 3);    // 0..63
    int qs4[4];
    qs4[0] = g; qs4[1] = 127 - g; qs4[2] = 128 + g; qs4[3] = 255 - g;
    const int qmax = qs4[3];

    const int tid  = threadIdx.x;
    const int lane = tid & 63;
    const int wid  = tid >> 6;
    const int r15  = lane & 15;   // MFMA free-dim (t) index
    const int quad = lane >> 4;   // MFMA k-group / s-row group

    __shared__ __bf16 K2sh[SS * HH];   // 32 KB, xor-swizzled 16B chunks
    __shared__ float qsh[4][HH];
    __shared__ float a_lds[4][SS];
    __shared__ float c_lds[4][SS];
    __shared__ float zred[4][4][HH];
    __shared__ float red[4][4];

    // ---- stage K2 (f32 -> bf16, swizzled) + the 4 q rows ---------------------
    {
        const int c4 = tid & 15;          // 4-float chunk within row
        const int c8 = c4 >> 1;           // 16B chunk index (0..7)
        const int half = (c4 & 1) * 4;    // low/high half of 16B chunk
        for (int it = 0; it < 16; ++it) {
            const int row = (tid >> 4) + it * 16;
            const float4 kv = *(const float4*)(K2b + ((n << 8) + row) * HH + c4 * 4);
            bf16x4 v;
            v[0] = (__bf16)kv.x; v[1] = (__bf16)kv.y;
            v[2] = (__bf16)kv.z; v[3] = (__bf16)kv.w;
            *(bf16x4*)&K2sh[row * HH + ((c8 ^ (row & 7)) << 3) + half] = v;
        }
        if (tid < 64) {
            const int qi = tid >> 4, c = tid & 15;
            const float4 qv = *(const float4*)(Qb + ((n << 8) + qs4[qi]) * HH + c * 4);
            *(float4*)&qsh[qi][c * 4] = qv;
        }
        #pragma unroll
        for (int qi = 0; qi < 4; ++qi) {
            const float init = (qs4[qi] < 2) ? (1.0f / SS) : 0.f;
            a_lds[qi][tid] = init;
            c_lds[qi][tid] = init;
        }
    }
    __syncthreads();

    // ---- score strips --------------------------------------------------------
    #pragma unroll
    for (int j = 0; j < 4; ++j) {
        int strip;
        if (j == 0) strip = wid;
        else if (j == 1) strip = 7 - wid;
        else if (j == 2) strip = 8 + wid;
        else strip = 15 - wid;
        const int s0 = strip << 4;
        if (s0 + 2 > qmax) continue;

        // k1 fragment rows (shared across the 4 q's)
        const float* k1p = K1b + ((n << 8) + s0 + r15) * HH;
        const float4 ka = *(const float4*)(k1p + quad * 8);
        const float4 kb = *(const float4*)(k1p + quad * 8 + 4);
        const float4 kc = *(const float4*)(k1p + 32 + quad * 8);
        const float4 kd = *(const float4*)(k1p + 32 + quad * 8 + 4);

        bf16x8 a0q[4], a1q[4];
        #pragma unroll
        for (int qi = 0; qi < 4; ++qi) {
            const float4 qa = *(const float4*)&qsh[qi][quad * 8];
            const float4 qb_ = *(const float4*)&qsh[qi][quad * 8 + 4];
            const float4 qc = *(const float4*)&qsh[qi][32 + quad * 8];
            const float4 qd = *(const float4*)&qsh[qi][32 + quad * 8 + 4];
            a0q[qi][0] = (__bf16)(ka.x * qa.x); a0q[qi][1] = (__bf16)(ka.y * qa.y);
            a0q[qi][2] = (__bf16)(ka.z * qa.z); a0q[qi][3] = (__bf16)(ka.w * qa.w);
            a0q[qi][4] = (__bf16)(kb.x * qb_.x); a0q[qi][5] = (__bf16)(kb.y * qb_.y);
            a0q[qi][6] = (__bf16)(kb.z * qb_.z); a0q[qi][7] = (__bf16)(kb.w * qb_.w);
            a1q[qi][0] = (__bf16)(kc.x * qc.x); a1q[qi][1] = (__bf16)(kc.y * qc.y);
            a1q[qi][2] = (__bf16)(kc.z * qc.z); a1q[qi][3] = (__bf16)(kc.w * qc.w);
            a1q[qi][4] = (__bf16)(kd.x * qd.x); a1q[qi][5] = (__bf16)(kd.y * qd.y);
            a1q[qi][6] = (__bf16)(kd.z * qd.z); a1q[qi][7] = (__bf16)(kd.w * qd.w);
        }

        float rowAcc[4][4] = {};
        const int swz = r15 & 7;
        for (int t0 = s0; t0 < qmax; t0 += 16) {
            const __bf16* K2row = &K2sh[(t0 + r15) * HH];
            const bf16x8 b0 = *(const bf16x8*)&K2row[((quad    ) ^ swz) << 3];
            const bf16x8 b1 = *(const bf16x8*)&K2row[((quad + 4) ^ swz) << 3];
            #pragma unroll
            for (int qi = 0; qi < 4; ++qi) {
                const int qv = qs4[qi];
                if (t0 >= qv || s0 + 2 > qv) continue;   // wave-uniform skip
                floatx4 C = {0.f, 0.f, 0.f, 0.f};
                C = __builtin_amdgcn_mfma_f32_16x16x32_bf16(a0q[qi], b0, C, 0, 0, 0);
                C = __builtin_amdgcn_mfma_f32_16x16x32_bf16(a1q[qi], b1, C, 0, 0, 0);

                float e[4];
                if (t0 >= s0 + 16 && t0 + 16 <= qv) {    // interior: no masking
                    #pragma unroll
                    for (int i = 0; i < 4; ++i) e[i] = __expf(C[i]);
                } else {
                    const int t = t0 + r15;
                    #pragma unroll
                    for (int i = 0; i < 4; ++i) {
                        const int s = s0 + quad * 4 + i;
                        e[i] = (s < t && t < qv) ? __expf(C[i]) : 0.f;
                    }
                }
                #pragma unroll
                for (int i = 0; i < 4; ++i) rowAcc[qi][i] += e[i];

                // column (t) sums: lanes {r15, r15+16, r15+32, r15+48}
                float cs = (e[0] + e[1]) + (e[2] + e[3]);
                cs += __shfl_xor(cs, 16, 64);
                cs += __shfl_xor(cs, 32, 64);
                if (lane < 16) atomicAdd(&c_lds[qi][t0 + r15], cs);
            }
        }
        // row (s) sums: butterfly over the 16 column-lanes; strip-exclusive rows
        #pragma unroll
        for (int qi = 0; qi < 4; ++qi) {
            if (s0 + 2 > qs4[qi]) continue;
            #pragma unroll
            for (int i = 0; i < 4; ++i) {
                rowAcc[qi][i] += __shfl_xor(rowAcc[qi][i], 1, 64);
                rowAcc[qi][i] += __shfl_xor(rowAcc[qi][i], 2, 64);
                rowAcc[qi][i] += __shfl_xor(rowAcc[qi][i], 4, 64);
                rowAcc[qi][i] += __shfl_xor(rowAcc[qi][i], 8, 64);
            }
            if (r15 == 0) {
                #pragma unroll
                for (int i = 0; i < 4; ++i)
                    a_lds[qi][s0 + quad * 4 + i] = rowAcc[qi][i];
            }
        }
    }
    __syncthreads();

    // ---- Z per q (q<2 presets sum to exactly 1.0 -> invZ = 1) ---------------
    #pragma unroll
    for (int qi = 0; qi < 4; ++qi) {
        float v = a_lds[qi][tid];
        #pragma unroll
        for (int off = 32; off >= 1; off >>= 1) v += __shfl_xor(v, off, 64);
        if (lane == 0) red[qi][wid] = v;
    }
    __syncthreads();
    float invZ[4];
    #pragma unroll
    for (int qi = 0; qi < 4; ++qi)
        invZ[qi] = 1.0f / (red[qi][0] + red[qi][1] + red[qi][2] + red[qi][3]);

    // ---- z = (sum_s a_s VA[s] + sum_t c_t VB[t]) * invZ + b_V12 --------------
    {
        const int h = lane;
        const int gg = wid;                 // s-range [gg*64, gg*64+64)
        const float* VAp = VAb + ((n << 8) + (gg << 6)) * HH + h;
        const float* VBp = VBb + ((n << 8) + (gg << 6)) * HH + h;
        float acc[4] = {0.f, 0.f, 0.f, 0.f};
        for (int i = 0; i < 64; ++i) {
            const float va = VAp[i * HH];
            const float vb = VBp[i * HH];
            const int si = (gg << 6) + i;
            #pragma unroll
            for (int qi = 0; qi < 4; ++qi)
                acc[qi] = fmaf(a_lds[qi][si], va,
                          fmaf(c_lds[qi][si], vb, acc[qi]));
        }
        #pragma unroll
        for (int qi = 0; qi < 4; ++qi) zred[qi][gg][h] = acc[qi];
    }
    __syncthreads();
    {
        const int qi = wid;                 // wave w writes q-row qs4[w]
        const int h = lane;
        const float zv = (zred[qi][0][h] + zred[qi][1][h] +
                          zred[qi][2][h] + zred[qi][3][h]) * invZ[qi]
                       + bV12[n * HH + h];
        zb[qs4[qi] * DD + n * HH + h] = zv;   // z row q = [n*64+h]
    }
}

// ---------------------------------------------------------------------------
// Kernel C: out[q,d] = sum_k z[q,k] * W_O[k,d] + b_O[d]   (f32)
// grid = 64 q-tiles * 4 d-quarters = 256 blocks, 256 threads.
// ---------------------------------------------------------------------------
__global__ __launch_bounds__(256) void out_kernel(
    const float* __restrict__ zb, const float* __restrict__ WO,
    const float* __restrict__ bO, float* __restrict__ out)
{
    const int q0 = (blockIdx.x >> 2) * 4;
    const int d0 = (blockIdx.x & 3) * 128;
    const int tid = threadIdx.x;
    const int lane = tid & 63;
    const int wid = tid >> 6;

    __shared__ float zsh[4][DD];      // 8 KB
    __shared__ float zpart[4][128];   // 2 KB

    for (int idx = tid; idx < 4 * DD; idx += 256) {
        const int r = idx >> 9, k = idx & 511;
        zsh[r][k] = zb[(q0 + r) * DD + k];
    }
    __syncthreads();

    const int qp = wid & 1;           // q-pair: rows {2qp, 2qp+1}
    const int kh = wid >> 1;          // k-half
    const int d = d0 + lane * 2;
    float2 acc0 = {0.f, 0.f}, acc1 = {0.f, 0.f};
    const int k0 = kh * 256;
    for (int k = k0; k < k0 + 256; k += 4) {
        #pragma unroll
        for (int u = 0; u < 4; ++u) {
            const float2 w = *(const float2*)(WO + (k + u) * DD + d);
            const float z0 = zsh[2 * qp + 0][k + u];
            const float z1 = zsh[2 * qp + 1][k + u];
            acc0.x = fmaf(z0, w.x, acc0.x); acc0.y = fmaf(z0, w.y, acc0.y);
            acc1.x = fmaf(z1, w.x, acc1.x); acc1.y = fmaf(z1, w.y, acc1.y);
        }
    }
    if (kh == 0) {
        *(float2*)&zpart[2 * qp + 0][lane * 2] = acc0;
        *(float2*)&zpart[2 * qp + 1][lane * 2] = acc1;
    }
    __syncthreads();
    if (kh == 1) {
        const float2 p0 = *(const float2*)&zpart[2 * qp + 0][lane * 2];
        const float2 p1 = *(const float2*)&zpart[2 * qp + 1][lane * 2];
        const float2 bv = *(const float2*)(bO + d);
        float2 o0, o1;
        o0.x = acc0.x + p0.x + bv.x; o0.y = acc0.y + p0.y + bv.y;
        o1.x = acc1.x + p1.x + bv.x; o1.y = acc1.y + p1.y + bv.y;
        *(float2*)(out + (q0 + 2 * qp + 0) * DD + d) = o0;
        *(float2*)(out + (q0 + 2 * qp + 1) * DD + d) = o1;
    }
}

// ---------------------------------------------------------------------------
extern "C" void kernel_launch(void* const* d_in, const int* in_sizes, int n_in,
                              void* d_out, int out_size, void* d_ws, size_t ws_size,
                              hipStream_t stream)
{
    const float* x    = (const float*)d_in[0];
    const float* WK1  = (const float*)d_in[1];
    const float* WK2  = (const float*)d_in[2];
    const float* WQ   = (const float*)d_in[3];
    const float* WV12 = (const float*)d_in[4];
    const float* WO   = (const float*)d_in[5];
    const float* bK1  = (const float*)d_in[6];
    const float* bK2  = (const float*)d_in[7];
    const float* bQ   = (const float*)d_in[8];
    const float* bV12 = (const float*)d_in[9];
    const float* bO   = (const float*)d_in[10];
    float* out = (float*)d_out;

    float* ws  = (float*)d_ws;
    const int T = NN * SS * HH;  // 131072 floats per projected tensor
    float* K1b = ws + 0 * T;
    float* K2b = ws + 1 * T;
    float* Qb  = ws + 2 * T;
    float* VAb = ws + 3 * T;
    float* VBb = ws + 4 * T;
    float* zb  = ws + 5 * T;

    proj_kernel<<<320, 512, 0, stream>>>(x, WK1, WK2, WQ, WV12,
                                         bK1, bK2, bQ,
                                         K1b, K2b, Qb, VAb, VBb);
    attn_kernel<<<512, 256, 0, stream>>>(K1b, K2b, Qb, VAb, VBb, bV12, zb);
    out_kernel<<<256, 256, 0, stream>>>(zb, WO, bO, out);
}

// Round 4
// 130.948 us; speedup vs baseline: 2.5956x; 1.1082x over previous
//
#include <hip/hip_runtime.h>

// Problem constants (B=1)
#define SS 256
#define DD 512
#define NN 8
#define HH 64

typedef __bf16 bf16x8 __attribute__((ext_vector_type(8)));
typedef __bf16 bf16x4 __attribute__((ext_vector_type(4)));
typedef float  floatx4 __attribute__((ext_vector_type(4)));

// ---------------------------------------------------------------------------
// Kernel A: projections via MFMA 16x16x32 bf16.
//   K1 = x@W_K1 + b_K1            -> f32 [n][256][64]
//   K2 = x@W_K2 + b_K2            -> bf16, xor-swizzled 16B chunks (attn LDS
//                                    layout: elem (p,h) at chunk (h>>3)^(p&7))
//   Qs = (x@W_Q + b_Q)/64         -> f32
//   VA = x@W_V12[:, :D]           -> f32
//   VB = x@W_V12[:, D:]           -> f32
// grid = 5 mats * 8 n * 8 ptiles(32 rows) = 320 blocks, 256 threads.
// x staged once per block as bf16 in swizzled LDS (A-frags); W converted
// f32->bf16 in-register (B-frags).  Compute: 671 MFLOP at MFMA rate.
// ---------------------------------------------------------------------------
__global__ __launch_bounds__(256) void proj_kernel(
    const float* __restrict__ x,
    const float* __restrict__ WK1, const float* __restrict__ WK2,
    const float* __restrict__ WQ,  const float* __restrict__ WV12,
    const float* __restrict__ bK1, const float* __restrict__ bK2,
    const float* __restrict__ bQ,
    float* __restrict__ K1b, float* __restrict__ Qb,
    float* __restrict__ VAb, float* __restrict__ VBb,
    __bf16* __restrict__ K2bf)
{
    const int blk = blockIdx.x;
    const int pt = blk & 7;         // 8 p-tiles of 32 rows
    const int n  = (blk >> 3) & 7;  // head
    const int m  = blk >> 6;        // which matrix (0..4)
    const int tid  = threadIdx.x;
    const int lane = tid & 63;
    const int wid  = tid >> 6;
    const int r15  = lane & 15;     // MFMA M/N index
    const int quad = lane >> 4;     // MFMA k-group / row-group
    const int p0 = pt * 32;

    __shared__ __bf16 xsh[32 * DD];   // 32 KB, xor-swizzled 16B chunks

    const float* W;
    if (m == 0)      W = WK1  + n * DD * HH;
    else if (m == 1) W = WK2  + n * DD * HH;
    else if (m == 2) W = WQ   + n * DD * HH;
    else if (m == 3) W = WV12 + n * 2 * DD * HH;
    else             W = WV12 + n * 2 * DD * HH + DD * HH;

    // ---- stage x rows p0..p0+31 (f32 -> bf16, swizzled) ----------------------
    for (int it = 0; it < 8; ++it) {
        const int idx = tid + it * 256;   // chunk id 0..2047 (32 rows x 64)
        const int row = idx >> 6;
        const int c8  = idx & 63;
        const float4 xa = *(const float4*)(x + (p0 + row) * DD + c8 * 8);
        const float4 xb = *(const float4*)(x + (p0 + row) * DD + c8 * 8 + 4);
        bf16x8 v;
        v[0]=(__bf16)xa.x; v[1]=(__bf16)xa.y; v[2]=(__bf16)xa.z; v[3]=(__bf16)xa.w;
        v[4]=(__bf16)xb.x; v[5]=(__bf16)xb.y; v[6]=(__bf16)xb.z; v[7]=(__bf16)xb.w;
        *(bf16x8*)&xsh[row * DD + ((c8 ^ (row & 7)) << 3)] = v;
    }
    __syncthreads();

    // ---- MFMA: wave w -> h-tile w, both p-sub-tiles; K = 512 -----------------
    const int h0 = wid << 4;
    const int swz = r15 & 7;          // row swizzle key (rows r15 and 16+r15 share)
    floatx4 C0 = {0.f,0.f,0.f,0.f}, C1 = {0.f,0.f,0.f,0.f};
    for (int kk = 0; kk < 16; ++kk) {
        const int c8 = (kk << 2) + quad;                 // 16B chunk of k-range
        const bf16x8 A0 = *(const bf16x8*)&xsh[ r15       * DD + ((c8 ^ swz) << 3)];
        const bf16x8 A1 = *(const bf16x8*)&xsh[(16 + r15) * DD + ((c8 ^ swz) << 3)];
        const float* Wp = W + (kk * 32 + quad * 8) * HH + h0 + r15;
        bf16x8 Bv;
        #pragma unroll
        for (int j = 0; j < 8; ++j) Bv[j] = (__bf16)Wp[j * HH];
        C0 = __builtin_amdgcn_mfma_f32_16x16x32_bf16(A0, Bv, C0, 0, 0, 0);
        C1 = __builtin_amdgcn_mfma_f32_16x16x32_bf16(A1, Bv, C1, 0, 0, 0);
    }

    // ---- epilogue: bias, scale, store (C: col=r15 -> h, row=quad*4+i -> p) ---
    float bv = 0.f;
    if (m == 0)      bv = bK1[n * HH + h0 + r15];
    else if (m == 1) bv = bK2[n * HH + h0 + r15];
    else if (m == 2) bv = bQ[n * HH + h0 + r15];

    if (m == 1) {
        const int h = h0 + r15;
        const int c8 = h >> 3;
        #pragma unroll
        for (int i = 0; i < 4; ++i) {
            int p = p0 + quad * 4 + i;
            K2bf[(n * SS + p) * HH + ((c8 ^ (p & 7)) << 3) + (h & 7)] =
                (__bf16)(C0[i] + bv);
            p += 16;
            K2bf[(n * SS + p) * HH + ((c8 ^ (p & 7)) << 3) + (h & 7)] =
                (__bf16)(C1[i] + bv);
        }
    } else {
        float* outb = (m == 0) ? K1b : (m == 2) ? Qb : (m == 3) ? VAb : VBb;
        const float scale = (m == 2) ? (1.0f / 64.0f) : 1.0f;  // fold 1/H into Q
        #pragma unroll
        for (int i = 0; i < 4; ++i) {
            const int p = p0 + quad * 4 + i;
            outb[(n * SS + p) * HH + h0 + r15]        = (C0[i] + bv) * scale;
            outb[(n * SS + p + 16) * HH + h0 + r15]   = (C1[i] + bv) * scale;
        }
    }
}

// ---------------------------------------------------------------------------
// Kernel B: block = (n, q-group of 4).  q-group {g, 127-g, 128+g, 255-g}.
// K2 staged as a straight 32KB bf16 copy (proj pre-swizzled it); A-frags per
// (strip, q) from global f32 k1 * LDS qs; B-frags shared across the 4 q's.
// Marginals a_s (register+butterfly) and c_t (LDS atomic) per q; masked
// entries are exactly 0 in the reference (exp underflow) so excluding them is
// exact; q<2 rows fully masked -> preset uniform 1/256 (Z sums to exactly 1).
// z[q,n,:] = (sum_s a_s VA[s] + sum_t c_t VB[t]) * invZ + b_V12.
// ---------------------------------------------------------------------------
__global__ __launch_bounds__(256, 3) void attn_kernel(
    const float* __restrict__ K1b, const __bf16* __restrict__ K2bf,
    const float* __restrict__ Qb,  const float* __restrict__ VAb,
    const float* __restrict__ VBb, const float* __restrict__ bV12,
    float* __restrict__ zb)
{
    const int n = blockIdx.x & 7;            // %8: same head -> same XCD L2
    const int g = (int)(blockIdx.x >> 3);    // 0..63
    int qs4[4];
    qs4[0] = g; qs4[1] = 127 - g; qs4[2] = 128 + g; qs4[3] = 255 - g;
    const int qmax = qs4[3];

    const int tid  = threadIdx.x;
    const int lane = tid & 63;
    const int wid  = tid >> 6;
    const int r15  = lane & 15;   // MFMA free-dim (t) index
    const int quad = lane >> 4;   // MFMA k-group / s-row group

    __shared__ __bf16 K2sh[SS * HH];   // 32 KB, already swizzled by proj
    __shared__ float qsh[4][HH];
    __shared__ float a_lds[4][SS];
    __shared__ float c_lds[4][SS];
    __shared__ float zred[4][4][HH];
    __shared__ float red[4][4];

    // ---- stage K2 (plain bf16 copy) + the 4 q rows ---------------------------
    {
        const __bf16* src = K2bf + (n << 8) * HH;
        for (int it = 0; it < 8; ++it) {
            const int idx = tid + it * 256;  // 2048 16B chunks
            *(bf16x8*)&K2sh[idx * 8] = *(const bf16x8*)&src[idx * 8];
        }
        if (tid < 64) {
            const int qi = tid >> 4, c = tid & 15;
            const float4 qv = *(const float4*)(Qb + ((n << 8) + qs4[qi]) * HH + c * 4);
            *(float4*)&qsh[qi][c * 4] = qv;
        }
        #pragma unroll
        for (int qi = 0; qi < 4; ++qi) {
            const float init = (qs4[qi] < 2) ? (1.0f / SS) : 0.f;
            a_lds[qi][tid] = init;
            c_lds[qi][tid] = init;
        }
    }
    __syncthreads();

    // ---- score strips --------------------------------------------------------
    #pragma unroll
    for (int j = 0; j < 4; ++j) {
        int strip;
        if (j == 0) strip = wid;
        else if (j == 1) strip = 7 - wid;
        else if (j == 2) strip = 8 + wid;
        else strip = 15 - wid;
        const int s0 = strip << 4;
        if (s0 + 2 > qmax) continue;

        // k1 fragment rows (shared across the 4 q's)
        const float* k1p = K1b + ((n << 8) + s0 + r15) * HH;
        const float4 ka = *(const float4*)(k1p + quad * 8);
        const float4 kb = *(const float4*)(k1p + quad * 8 + 4);
        const float4 kc = *(const float4*)(k1p + 32 + quad * 8);
        const float4 kd = *(const float4*)(k1p + 32 + quad * 8 + 4);

        bf16x8 a0q[4], a1q[4];
        #pragma unroll
        for (int qi = 0; qi < 4; ++qi) {
            const float4 qa = *(const float4*)&qsh[qi][quad * 8];
            const float4 qb_ = *(const float4*)&qsh[qi][quad * 8 + 4];
            const float4 qc = *(const float4*)&qsh[qi][32 + quad * 8];
            const float4 qd = *(const float4*)&qsh[qi][32 + quad * 8 + 4];
            a0q[qi][0] = (__bf16)(ka.x * qa.x); a0q[qi][1] = (__bf16)(ka.y * qa.y);
            a0q[qi][2] = (__bf16)(ka.z * qa.z); a0q[qi][3] = (__bf16)(ka.w * qa.w);
            a0q[qi][4] = (__bf16)(kb.x * qb_.x); a0q[qi][5] = (__bf16)(kb.y * qb_.y);
            a0q[qi][6] = (__bf16)(kb.z * qb_.z); a0q[qi][7] = (__bf16)(kb.w * qb_.w);
            a1q[qi][0] = (__bf16)(kc.x * qc.x); a1q[qi][1] = (__bf16)(kc.y * qc.y);
            a1q[qi][2] = (__bf16)(kc.z * qc.z); a1q[qi][3] = (__bf16)(kc.w * qc.w);
            a1q[qi][4] = (__bf16)(kd.x * qd.x); a1q[qi][5] = (__bf16)(kd.y * qd.y);
            a1q[qi][6] = (__bf16)(kd.z * qd.z); a1q[qi][7] = (__bf16)(kd.w * qd.w);
        }

        float rowAcc[4][4] = {};
        const int swz = r15 & 7;
        for (int t0 = s0; t0 < qmax; t0 += 16) {
            const __bf16* K2row = &K2sh[(t0 + r15) * HH];
            const bf16x8 b0 = *(const bf16x8*)&K2row[((quad    ) ^ swz) << 3];
            const bf16x8 b1 = *(const bf16x8*)&K2row[((quad + 4) ^ swz) << 3];
            #pragma unroll
            for (int qi = 0; qi < 4; ++qi) {
                const int qv = qs4[qi];
                if (t0 >= qv || s0 + 2 > qv) continue;   // wave-uniform skip
                floatx4 C = {0.f, 0.f, 0.f, 0.f};
                C = __builtin_amdgcn_mfma_f32_16x16x32_bf16(a0q[qi], b0, C, 0, 0, 0);
                C = __builtin_amdgcn_mfma_f32_16x16x32_bf16(a1q[qi], b1, C, 0, 0, 0);

                float e[4];
                if (t0 >= s0 + 16 && t0 + 16 <= qv) {    // interior: no masking
                    #pragma unroll
                    for (int i = 0; i < 4; ++i) e[i] = __expf(C[i]);
                } else {
                    const int t = t0 + r15;
                    #pragma unroll
                    for (int i = 0; i < 4; ++i) {
                        const int s = s0 + quad * 4 + i;
                        e[i] = (s < t && t < qv) ? __expf(C[i]) : 0.f;
                    }
                }
                #pragma unroll
                for (int i = 0; i < 4; ++i) rowAcc[qi][i] += e[i];

                // column (t) sums: lanes {r15, r15+16, r15+32, r15+48}
                float cs = (e[0] + e[1]) + (e[2] + e[3]);
                cs += __shfl_xor(cs, 16, 64);
                cs += __shfl_xor(cs, 32, 64);
                if (lane < 16) atomicAdd(&c_lds[qi][t0 + r15], cs);
            }
        }
        // row (s) sums: butterfly over the 16 column-lanes; strip-exclusive rows
        #pragma unroll
        for (int qi = 0; qi < 4; ++qi) {
            if (s0 + 2 > qs4[qi]) continue;
            #pragma unroll
            for (int i = 0; i < 4; ++i) {
                rowAcc[qi][i] += __shfl_xor(rowAcc[qi][i], 1, 64);
                rowAcc[qi][i] += __shfl_xor(rowAcc[qi][i], 2, 64);
                rowAcc[qi][i] += __shfl_xor(rowAcc[qi][i], 4, 64);
                rowAcc[qi][i] += __shfl_xor(rowAcc[qi][i], 8, 64);
            }
            if (r15 == 0) {
                #pragma unroll
                for (int i = 0; i < 4; ++i)
                    a_lds[qi][s0 + quad * 4 + i] = rowAcc[qi][i];
            }
        }
    }
    __syncthreads();

    // ---- Z per q (q<2 presets sum to exactly 1.0 -> invZ = 1) ---------------
    #pragma unroll
    for (int qi = 0; qi < 4; ++qi) {
        float v = a_lds[qi][tid];
        #pragma unroll
        for (int off = 32; off >= 1; off >>= 1) v += __shfl_xor(v, off, 64);
        if (lane == 0) red[qi][wid] = v;
    }
    __syncthreads();
    float invZ[4];
    #pragma unroll
    for (int qi = 0; qi < 4; ++qi)
        invZ[qi] = 1.0f / (red[qi][0] + red[qi][1] + red[qi][2] + red[qi][3]);

    // ---- z = (sum_s a_s VA[s] + sum_t c_t VB[t]) * invZ + b_V12 --------------
    {
        const int h = lane;
        const int gg = wid;                 // s-range [gg*64, gg*64+64)
        const float* VAp = VAb + ((n << 8) + (gg << 6)) * HH + h;
        const float* VBp = VBb + ((n << 8) + (gg << 6)) * HH + h;
        float acc[4] = {0.f, 0.f, 0.f, 0.f};
        for (int i = 0; i < 64; ++i) {
            const float va = VAp[i * HH];
            const float vb = VBp[i * HH];
            const int si = (gg << 6) + i;
            #pragma unroll
            for (int qi = 0; qi < 4; ++qi)
                acc[qi] = fmaf(a_lds[qi][si], va,
                          fmaf(c_lds[qi][si], vb, acc[qi]));
        }
        #pragma unroll
        for (int qi = 0; qi < 4; ++qi) zred[qi][gg][h] = acc[qi];
    }
    __syncthreads();
    {
        const int qi = wid;                 // wave w writes q-row qs4[w]
        const int h = lane;
        const float zv = (zred[qi][0][h] + zred[qi][1][h] +
                          zred[qi][2][h] + zred[qi][3][h]) * invZ[qi]
                       + bV12[n * HH + h];
        zb[qs4[qi] * DD + n * HH + h] = zv;   // z row q = [n*64+h]
    }
}

// ---------------------------------------------------------------------------
// Kernel C: out[q,d] = sum_k z[q,k] * W_O[k,d] + b_O[d]   (f32)
// grid = 64 q-tiles * 4 d-quarters = 256 blocks, 256 threads.
// ---------------------------------------------------------------------------
__global__ __launch_bounds__(256) void out_kernel(
    const float* __restrict__ zb, const float* __restrict__ WO,
    const float* __restrict__ bO, float* __restrict__ out)
{
    const int q0 = (blockIdx.x >> 2) * 4;
    const int d0 = (blockIdx.x & 3) * 128;
    const int tid = threadIdx.x;
    const int lane = tid & 63;
    const int wid = tid >> 6;

    __shared__ float zsh[4][DD];      // 8 KB
    __shared__ float zpart[4][128];   // 2 KB

    for (int idx = tid; idx < 4 * DD; idx += 256) {
        const int r = idx >> 9, k = idx & 511;
        zsh[r][k] = zb[(q0 + r) * DD + k];
    }
    __syncthreads();

    const int qp = wid & 1;           // q-pair: rows {2qp, 2qp+1}
    const int kh = wid >> 1;          // k-half
    const int d = d0 + lane * 2;
    float2 acc0 = {0.f, 0.f}, acc1 = {0.f, 0.f};
    const int k0 = kh * 256;
    for (int k = k0; k < k0 + 256; k += 4) {
        #pragma unroll
        for (int u = 0; u < 4; ++u) {
            const float2 w = *(const float2*)(WO + (k + u) * DD + d);
            const float z0 = zsh[2 * qp + 0][k + u];
            const float z1 = zsh[2 * qp + 1][k + u];
            acc0.x = fmaf(z0, w.x, acc0.x); acc0.y = fmaf(z0, w.y, acc0.y);
            acc1.x = fmaf(z1, w.x, acc1.x); acc1.y = fmaf(z1, w.y, acc1.y);
        }
    }
    if (kh == 0) {
        *(float2*)&zpart[2 * qp + 0][lane * 2] = acc0;
        *(float2*)&zpart[2 * qp + 1][lane * 2] = acc1;
    }
    __syncthreads();
    if (kh == 1) {
        const float2 p0 = *(const float2*)&zpart[2 * qp + 0][lane * 2];
        const float2 p1 = *(const float2*)&zpart[2 * qp + 1][lane * 2];
        const float2 bv = *(const float2*)(bO + d);
        float2 o0, o1;
        o0.x = acc0.x + p0.x + bv.x; o0.y = acc0.y + p0.y + bv.y;
        o1.x = acc1.x + p1.x + bv.x; o1.y = acc1.y + p1.y + bv.y;
        *(float2*)(out + (q0 + 2 * qp + 0) * DD + d) = o0;
        *(float2*)(out + (q0 + 2 * qp + 1) * DD + d) = o1;
    }
}

// ---------------------------------------------------------------------------
extern "C" void kernel_launch(void* const* d_in, const int* in_sizes, int n_in,
                              void* d_out, int out_size, void* d_ws, size_t ws_size,
                              hipStream_t stream)
{
    const float* x    = (const float*)d_in[0];
    const float* WK1  = (const float*)d_in[1];
    const float* WK2  = (const float*)d_in[2];
    const float* WQ   = (const float*)d_in[3];
    const float* WV12 = (const float*)d_in[4];
    const float* WO   = (const float*)d_in[5];
    const float* bK1  = (const float*)d_in[6];
    const float* bK2  = (const float*)d_in[7];
    const float* bQ   = (const float*)d_in[8];
    const float* bV12 = (const float*)d_in[9];
    const float* bO   = (const float*)d_in[10];
    float* out = (float*)d_out;

    float* ws  = (float*)d_ws;
    const int T = NN * SS * HH;  // 131072 floats per projected tensor
    float* K1b = ws + 0 * T;
    float* Qb  = ws + 1 * T;
    float* VAb = ws + 2 * T;
    float* VBb = ws + 3 * T;
    float* zb  = ws + 4 * T;           // 256*512 floats
    __bf16* K2bf = (__bf16*)(ws + 5 * T);  // 131072 bf16 (pre-swizzled)

    proj_kernel<<<320, 256, 0, stream>>>(x, WK1, WK2, WQ, WV12,
                                         bK1, bK2, bQ,
                                         K1b, Qb, VAb, VBb, K2bf);
    attn_kernel<<<512, 256, 0, stream>>>(K1b, K2bf, Qb, VAb, VBb, bV12, zb);
    out_kernel<<<256, 256, 0, stream>>>(zb, WO, bO, out);
}

// Round 5
// 127.411 us; speedup vs baseline: 2.6677x; 1.0278x over previous
//
#include <hip/hip_runtime.h>

// Problem constants (B=1)
#define SS 256
#define DD 512
#define NN 8
#define HH 64

typedef __bf16 bf16x8 __attribute__((ext_vector_type(8)));
typedef __bf16 bf16x4 __attribute__((ext_vector_type(4)));
typedef float  floatx4 __attribute__((ext_vector_type(4)));

// ---------------------------------------------------------------------------
// Kernel A: projections via MFMA 16x16x32 bf16.
//   m=0: K1 = x@W_K1 + b_K1      -> f32 [n][256][64]
//   m=1: K2 = x@W_K2 + b_K2      -> bf16, xor-swizzled 16B chunks (attn LDS
//                                   layout: elem (p,h) at chunk (h>>3)^(p&7))
//   m=2: Qs = (x@W_Q + b_Q)/64   -> f32
//   m=3: VA = x@W_V12[:, :D]     -> bf16 plain [n][256][64]
//   m=4: VB = x@W_V12[:, D:]     -> bf16 plain
//   m=5: out[q,:] = b_O          (bias init for attn's atomic accumulation;
//                                 stream order guarantees visibility)
// grid = 6*64 = 384 blocks, 256 threads.
// ---------------------------------------------------------------------------
__global__ __launch_bounds__(256) void proj_kernel(
    const float* __restrict__ x,
    const float* __restrict__ WK1, const float* __restrict__ WK2,
    const float* __restrict__ WQ,  const float* __restrict__ WV12,
    const float* __restrict__ bK1, const float* __restrict__ bK2,
    const float* __restrict__ bQ,  const float* __restrict__ bO,
    float* __restrict__ K1b, float* __restrict__ Qb,
    __bf16* __restrict__ K2bf, __bf16* __restrict__ VAbf,
    __bf16* __restrict__ VBbf, float* __restrict__ outp)
{
    const int blk = blockIdx.x;
    const int m  = blk >> 6;        // which matrix (0..5)
    const int tid  = threadIdx.x;

    __shared__ __bf16 xsh[32 * DD];   // 32 KB, xor-swizzled 16B chunks

    if (m == 5) {                     // bias init of out (whole block branches)
        const int idx = blk & 63;
        const int q = idx * 4 + (tid >> 6);
        const int d = (tid & 63) * 8;
        const float4 b0 = *(const float4*)(bO + d);
        const float4 b1 = *(const float4*)(bO + d + 4);
        *(float4*)(outp + q * DD + d)     = b0;
        *(float4*)(outp + q * DD + d + 4) = b1;
        return;
    }

    const int pt = blk & 7;         // 8 p-tiles of 32 rows
    const int n  = (blk >> 3) & 7;  // head
    const int lane = tid & 63;
    const int wid  = tid >> 6;
    const int r15  = lane & 15;     // MFMA M/N index
    const int quad = lane >> 4;     // MFMA k-group / row-group
    const int p0 = pt * 32;

    const float* W;
    if (m == 0)      W = WK1  + n * DD * HH;
    else if (m == 1) W = WK2  + n * DD * HH;
    else if (m == 2) W = WQ   + n * DD * HH;
    else if (m == 3) W = WV12 + n * 2 * DD * HH;
    else             W = WV12 + n * 2 * DD * HH + DD * HH;

    // ---- stage x rows p0..p0+31 (f32 -> bf16, swizzled) ----------------------
    for (int it = 0; it < 8; ++it) {
        const int idx = tid + it * 256;   // chunk id 0..2047 (32 rows x 64)
        const int row = idx >> 6;
        const int c8  = idx & 63;
        const float4 xa = *(const float4*)(x + (p0 + row) * DD + c8 * 8);
        const float4 xb = *(const float4*)(x + (p0 + row) * DD + c8 * 8 + 4);
        bf16x8 v;
        v[0]=(__bf16)xa.x; v[1]=(__bf16)xa.y; v[2]=(__bf16)xa.z; v[3]=(__bf16)xa.w;
        v[4]=(__bf16)xb.x; v[5]=(__bf16)xb.y; v[6]=(__bf16)xb.z; v[7]=(__bf16)xb.w;
        *(bf16x8*)&xsh[row * DD + ((c8 ^ (row & 7)) << 3)] = v;
    }
    __syncthreads();

    // ---- MFMA: wave w -> h-tile w, both p-sub-tiles; K = 512 -----------------
    const int h0 = wid << 4;
    const int swz = r15 & 7;          // row swizzle key
    floatx4 C0 = {0.f,0.f,0.f,0.f}, C1 = {0.f,0.f,0.f,0.f};
    for (int kk = 0; kk < 16; ++kk) {
        const int c8 = (kk << 2) + quad;                 // 16B chunk of k-range
        const bf16x8 A0 = *(const bf16x8*)&xsh[ r15       * DD + ((c8 ^ swz) << 3)];
        const bf16x8 A1 = *(const bf16x8*)&xsh[(16 + r15) * DD + ((c8 ^ swz) << 3)];
        const float* Wp = W + (kk * 32 + quad * 8) * HH + h0 + r15;
        bf16x8 Bv;
        #pragma unroll
        for (int j = 0; j < 8; ++j) Bv[j] = (__bf16)Wp[j * HH];
        C0 = __builtin_amdgcn_mfma_f32_16x16x32_bf16(A0, Bv, C0, 0, 0, 0);
        C1 = __builtin_amdgcn_mfma_f32_16x16x32_bf16(A1, Bv, C1, 0, 0, 0);
    }

    // ---- epilogue: bias, scale, store (C: col=r15 -> h, row=quad*4+i -> p) ---
    float bv = 0.f;
    if (m == 0)      bv = bK1[n * HH + h0 + r15];
    else if (m == 1) bv = bK2[n * HH + h0 + r15];
    else if (m == 2) bv = bQ[n * HH + h0 + r15];

    if (m == 1) {
        const int h = h0 + r15;
        const int c8 = h >> 3;
        #pragma unroll
        for (int i = 0; i < 4; ++i) {
            int p = p0 + quad * 4 + i;
            K2bf[(n * SS + p) * HH + ((c8 ^ (p & 7)) << 3) + (h & 7)] =
                (__bf16)(C0[i] + bv);
            p += 16;
            K2bf[(n * SS + p) * HH + ((c8 ^ (p & 7)) << 3) + (h & 7)] =
                (__bf16)(C1[i] + bv);
        }
    } else if (m >= 3) {
        __bf16* outb = (m == 3) ? VAbf : VBbf;
        #pragma unroll
        for (int i = 0; i < 4; ++i) {
            const int p = p0 + quad * 4 + i;
            outb[(n * SS + p) * HH + h0 + r15]      = (__bf16)C0[i];
            outb[(n * SS + p + 16) * HH + h0 + r15] = (__bf16)C1[i];
        }
    } else {
        float* outb = (m == 0) ? K1b : Qb;
        const float scale = (m == 2) ? (1.0f / 64.0f) : 1.0f;  // fold 1/H into Q
        #pragma unroll
        for (int i = 0; i < 4; ++i) {
            const int p = p0 + quad * 4 + i;
            outb[(n * SS + p) * HH + h0 + r15]      = (C0[i] + bv) * scale;
            outb[(n * SS + p + 16) * HH + h0 + r15] = (C1[i] + bv) * scale;
        }
    }
}

// ---------------------------------------------------------------------------
// Kernel B: block = (n, q-group of 4).  q-group {g, 127-g, 128+g, 255-g}.
// K2 staged as a straight 32KB bf16 copy (proj pre-swizzled it); A-frags per
// (strip, q) from global f32 k1 * LDS qs; B-frags shared across the 4 q's.
// Marginals a_s (register+butterfly) and c_t (LDS atomic) per q; masked
// entries are exactly 0 in the reference (exp underflow) so excluding them is
// exact; q<2 rows fully masked -> preset uniform 1/256 (Z sums to exactly 1).
// z[q,n,:] = (sum_s a_s VA[s] + sum_t c_t VB[t]) * invZ + b_V12, then this
// block's out-contribution z . WO[n*64:(n+1)*64, :] is atomicAdd-ed into out
// (bias pre-written by proj; stream order + device-scope atomics = safe).
// ---------------------------------------------------------------------------
__global__ __launch_bounds__(256, 3) void attn_kernel(
    const float* __restrict__ K1b, const __bf16* __restrict__ K2bf,
    const float* __restrict__ Qb,  const __bf16* __restrict__ VAbf,
    const __bf16* __restrict__ VBbf, const float* __restrict__ bV12,
    const float* __restrict__ WO, float* __restrict__ outp)
{
    const int n = blockIdx.x & 7;            // %8: same head -> same XCD L2
    const int g = (int)(blockIdx.x >> 3);    // 0..63
    int qs4[4];
    qs4[0] = g; qs4[1] = 127 - g; qs4[2] = 128 + g; qs4[3] = 255 - g;
    const int qmax = qs4[3];

    const int tid  = threadIdx.x;
    const int lane = tid & 63;
    const int wid  = tid >> 6;
    const int r15  = lane & 15;   // MFMA free-dim (t) index
    const int quad = lane >> 4;   // MFMA k-group / s-row group

    __shared__ __bf16 K2sh[SS * HH];   // 32 KB, already swizzled by proj
    __shared__ float qsh[4][HH];       // q rows; later reused for final z rows
    __shared__ float a_lds[4][SS];
    __shared__ float c_lds[4][SS];
    __shared__ float zred[4][4][HH];
    __shared__ float red[4][4];

    // ---- stage K2 (plain bf16 copy) + the 4 q rows ---------------------------
    {
        const __bf16* src = K2bf + (n << 8) * HH;
        for (int it = 0; it < 8; ++it) {
            const int idx = tid + it * 256;  // 2048 16B chunks
            *(bf16x8*)&K2sh[idx * 8] = *(const bf16x8*)&src[idx * 8];
        }
        if (tid < 64) {
            const int qi = tid >> 4, c = tid & 15;
            const float4 qv = *(const float4*)(Qb + ((n << 8) + qs4[qi]) * HH + c * 4);
            *(float4*)&qsh[qi][c * 4] = qv;
        }
        #pragma unroll
        for (int qi = 0; qi < 4; ++qi) {
            const float init = (qs4[qi] < 2) ? (1.0f / SS) : 0.f;
            a_lds[qi][tid] = init;
            c_lds[qi][tid] = init;
        }
    }
    __syncthreads();

    // ---- score strips --------------------------------------------------------
    #pragma unroll
    for (int j = 0; j < 4; ++j) {
        int strip;
        if (j == 0) strip = wid;
        else if (j == 1) strip = 7 - wid;
        else if (j == 2) strip = 8 + wid;
        else strip = 15 - wid;
        const int s0 = strip << 4;
        if (s0 + 2 > qmax) continue;

        // k1 fragment rows (shared across the 4 q's)
        const float* k1p = K1b + ((n << 8) + s0 + r15) * HH;
        const float4 ka = *(const float4*)(k1p + quad * 8);
        const float4 kb = *(const float4*)(k1p + quad * 8 + 4);
        const float4 kc = *(const float4*)(k1p + 32 + quad * 8);
        const float4 kd = *(const float4*)(k1p + 32 + quad * 8 + 4);

        bf16x8 a0q[4], a1q[4];
        #pragma unroll
        for (int qi = 0; qi < 4; ++qi) {
            const float4 qa = *(const float4*)&qsh[qi][quad * 8];
            const float4 qb_ = *(const float4*)&qsh[qi][quad * 8 + 4];
            const float4 qc = *(const float4*)&qsh[qi][32 + quad * 8];
            const float4 qd = *(const float4*)&qsh[qi][32 + quad * 8 + 4];
            a0q[qi][0] = (__bf16)(ka.x * qa.x); a0q[qi][1] = (__bf16)(ka.y * qa.y);
            a0q[qi][2] = (__bf16)(ka.z * qa.z); a0q[qi][3] = (__bf16)(ka.w * qa.w);
            a0q[qi][4] = (__bf16)(kb.x * qb_.x); a0q[qi][5] = (__bf16)(kb.y * qb_.y);
            a0q[qi][6] = (__bf16)(kb.z * qb_.z); a0q[qi][7] = (__bf16)(kb.w * qb_.w);
            a1q[qi][0] = (__bf16)(kc.x * qc.x); a1q[qi][1] = (__bf16)(kc.y * qc.y);
            a1q[qi][2] = (__bf16)(kc.z * qc.z); a1q[qi][3] = (__bf16)(kc.w * qc.w);
            a1q[qi][4] = (__bf16)(kd.x * qd.x); a1q[qi][5] = (__bf16)(kd.y * qd.y);
            a1q[qi][6] = (__bf16)(kd.z * qd.z); a1q[qi][7] = (__bf16)(kd.w * qd.w);
        }

        float rowAcc[4][4] = {};
        const int swz = r15 & 7;
        for (int t0 = s0; t0 < qmax; t0 += 16) {
            const __bf16* K2row = &K2sh[(t0 + r15) * HH];
            const bf16x8 b0 = *(const bf16x8*)&K2row[((quad    ) ^ swz) << 3];
            const bf16x8 b1 = *(const bf16x8*)&K2row[((quad + 4) ^ swz) << 3];
            #pragma unroll
            for (int qi = 0; qi < 4; ++qi) {
                const int qv = qs4[qi];
                if (t0 >= qv || s0 + 2 > qv) continue;   // wave-uniform skip
                floatx4 C = {0.f, 0.f, 0.f, 0.f};
                C = __builtin_amdgcn_mfma_f32_16x16x32_bf16(a0q[qi], b0, C, 0, 0, 0);
                C = __builtin_amdgcn_mfma_f32_16x16x32_bf16(a1q[qi], b1, C, 0, 0, 0);

                float e[4];
                if (t0 >= s0 + 16 && t0 + 16 <= qv) {    // interior: no masking
                    #pragma unroll
                    for (int i = 0; i < 4; ++i) e[i] = __expf(C[i]);
                } else {
                    const int t = t0 + r15;
                    #pragma unroll
                    for (int i = 0; i < 4; ++i) {
                        const int s = s0 + quad * 4 + i;
                        e[i] = (s < t && t < qv) ? __expf(C[i]) : 0.f;
                    }
                }
                #pragma unroll
                for (int i = 0; i < 4; ++i) rowAcc[qi][i] += e[i];

                // column (t) sums: lanes {r15, r15+16, r15+32, r15+48}
                float cs = (e[0] + e[1]) + (e[2] + e[3]);
                cs += __shfl_xor(cs, 16, 64);
                cs += __shfl_xor(cs, 32, 64);
                if (lane < 16) atomicAdd(&c_lds[qi][t0 + r15], cs);
            }
        }
        // row (s) sums: butterfly over the 16 column-lanes; strip-exclusive rows
        #pragma unroll
        for (int qi = 0; qi < 4; ++qi) {
            if (s0 + 2 > qs4[qi]) continue;
            #pragma unroll
            for (int i = 0; i < 4; ++i) {
                rowAcc[qi][i] += __shfl_xor(rowAcc[qi][i], 1, 64);
                rowAcc[qi][i] += __shfl_xor(rowAcc[qi][i], 2, 64);
                rowAcc[qi][i] += __shfl_xor(rowAcc[qi][i], 4, 64);
                rowAcc[qi][i] += __shfl_xor(rowAcc[qi][i], 8, 64);
            }
            if (r15 == 0) {
                #pragma unroll
                for (int i = 0; i < 4; ++i)
                    a_lds[qi][s0 + quad * 4 + i] = rowAcc[qi][i];
            }
        }
    }
    __syncthreads();

    // ---- Z per q (q<2 presets sum to exactly 1.0 -> invZ = 1) ---------------
    #pragma unroll
    for (int qi = 0; qi < 4; ++qi) {
        float v = a_lds[qi][tid];
        #pragma unroll
        for (int off = 32; off >= 1; off >>= 1) v += __shfl_xor(v, off, 64);
        if (lane == 0) red[qi][wid] = v;
    }
    __syncthreads();
    float invZ[4];
    #pragma unroll
    for (int qi = 0; qi < 4; ++qi)
        invZ[qi] = 1.0f / (red[qi][0] + red[qi][1] + red[qi][2] + red[qi][3]);

    // ---- z = (sum_s a_s VA[s] + sum_t c_t VB[t]) * invZ + b_V12 --------------
    {
        const int h = lane;
        const int gg = wid;                 // s-range [gg*64, gg*64+64)
        const __bf16* VAp = VAbf + ((n << 8) + (gg << 6)) * HH + h;
        const __bf16* VBp = VBbf + ((n << 8) + (gg << 6)) * HH + h;
        float acc[4] = {0.f, 0.f, 0.f, 0.f};
        for (int i = 0; i < 64; ++i) {
            const float va = (float)VAp[i * HH];
            const float vb = (float)VBp[i * HH];
            const int si = (gg << 6) + i;
            #pragma unroll
            for (int qi = 0; qi < 4; ++qi)
                acc[qi] = fmaf(a_lds[qi][si], va,
                          fmaf(c_lds[qi][si], vb, acc[qi]));
        }
        #pragma unroll
        for (int qi = 0; qi < 4; ++qi) zred[qi][gg][h] = acc[qi];
    }
    __syncthreads();
    {   // final z rows into qsh (reused; q-row reads are done)
        const int qi = wid;
        const int h = lane;
        qsh[qi][h] = (zred[qi][0][h] + zred[qi][1][h] +
                      zred[qi][2][h] + zred[qi][3][h]) * invZ[qi]
                   + bV12[n * HH + h];
    }
    __syncthreads();

    // ---- fused epilogue GEMM: out[q,:] += z[q, n-slice] . WO[n*64:, :] -------
    {
        const int qi = wid;
        const int q  = qs4[qi];
        const int d0 = lane * 4;
        const float* WOp = WO + (n * HH) * DD;
        floatx4 acc0 = {0.f,0.f,0.f,0.f}, acc1 = {0.f,0.f,0.f,0.f};
        for (int h = 0; h < HH; ++h) {
            const float zv = qsh[qi][h];           // wave-uniform broadcast
            const float4 w0 = *(const float4*)(WOp + h * DD + d0);
            const float4 w1 = *(const float4*)(WOp + h * DD + d0 + 256);
            acc0[0] = fmaf(zv, w0.x, acc0[0]); acc0[1] = fmaf(zv, w0.y, acc0[1]);
            acc0[2] = fmaf(zv, w0.z, acc0[2]); acc0[3] = fmaf(zv, w0.w, acc0[3]);
            acc1[0] = fmaf(zv, w1.x, acc1[0]); acc1[1] = fmaf(zv, w1.y, acc1[1]);
            acc1[2] = fmaf(zv, w1.z, acc1[2]); acc1[3] = fmaf(zv, w1.w, acc1[3]);
        }
        float* op = outp + q * DD;
        #pragma unroll
        for (int i = 0; i < 4; ++i) {
            atomicAdd(op + d0 + i,       acc0[i]);
            atomicAdd(op + d0 + 256 + i, acc1[i]);
        }
    }
}

// ---------------------------------------------------------------------------
extern "C" void kernel_launch(void* const* d_in, const int* in_sizes, int n_in,
                              void* d_out, int out_size, void* d_ws, size_t ws_size,
                              hipStream_t stream)
{
    const float* x    = (const float*)d_in[0];
    const float* WK1  = (const float*)d_in[1];
    const float* WK2  = (const float*)d_in[2];
    const float* WQ   = (const float*)d_in[3];
    const float* WV12 = (const float*)d_in[4];
    const float* WO   = (const float*)d_in[5];
    const float* bK1  = (const float*)d_in[6];
    const float* bK2  = (const float*)d_in[7];
    const float* bQ   = (const float*)d_in[8];
    const float* bV12 = (const float*)d_in[9];
    const float* bO   = (const float*)d_in[10];
    float* out = (float*)d_out;

    float* ws  = (float*)d_ws;
    const int T = NN * SS * HH;  // 131072 elements per projected tensor
    float*  K1b  = ws + 0 * T;
    float*  Qb   = ws + 1 * T;
    __bf16* b16  = (__bf16*)(ws + 2 * T);
    __bf16* K2bf = b16 + 0 * T;   // pre-swizzled
    __bf16* VAbf = b16 + 1 * T;
    __bf16* VBbf = b16 + 2 * T;

    proj_kernel<<<384, 256, 0, stream>>>(x, WK1, WK2, WQ, WV12,
                                         bK1, bK2, bQ, bO,
                                         K1b, Qb, K2bf, VAbf, VBbf, out);
    attn_kernel<<<512, 256, 0, stream>>>(K1b, K2bf, Qb, VAbf, VBbf, bV12,
                                         WO, out);
}

// Round 6
// 118.731 us; speedup vs baseline: 2.8627x; 1.0731x over previous
//
#include <hip/hip_runtime.h>

// Problem constants (B=1)
#define SS 256
#define DD 512
#define NN 8
#define HH 64

typedef __bf16 bf16x8 __attribute__((ext_vector_type(8)));
typedef __bf16 bf16x4 __attribute__((ext_vector_type(4)));
typedef float  floatx4 __attribute__((ext_vector_type(4)));

// ---------------------------------------------------------------------------
// Kernel A: projections via MFMA 16x16x32 bf16.
//   m=0: K1 = x@W_K1 + b_K1      -> f32 [n][256][64]
//   m=1: K2 = x@W_K2 + b_K2      -> bf16, xor-swizzled 16B chunks (attn LDS
//                                   layout: elem (p,h) at chunk (h>>3)^(p&7))
//   m=2: Qs = (x@W_Q + b_Q)/64   -> f32
//   m=3: VA = x@W_V12[:, :D]     -> bf16 plain [n][256][64]
//   m=4: VB = x@W_V12[:, D:]     -> bf16 plain
//   m=5: out[q,:] = b_O          (bias init for attn's atomic accumulation;
//                                 stream order guarantees visibility)
// grid = 6*64 = 384 blocks, 256 threads.
// ---------------------------------------------------------------------------
__global__ __launch_bounds__(256) void proj_kernel(
    const float* __restrict__ x,
    const float* __restrict__ WK1, const float* __restrict__ WK2,
    const float* __restrict__ WQ,  const float* __restrict__ WV12,
    const float* __restrict__ bK1, const float* __restrict__ bK2,
    const float* __restrict__ bQ,  const float* __restrict__ bO,
    float* __restrict__ K1b, float* __restrict__ Qb,
    __bf16* __restrict__ K2bf, __bf16* __restrict__ VAbf,
    __bf16* __restrict__ VBbf, float* __restrict__ outp)
{
    const int blk = blockIdx.x;
    const int m  = blk >> 6;        // which matrix (0..5)
    const int tid  = threadIdx.x;

    __shared__ __bf16 xsh[32 * DD];   // 32 KB, xor-swizzled 16B chunks

    if (m == 5) {                     // bias init of out (whole block branches)
        const int idx = blk & 63;
        const int q = idx * 4 + (tid >> 6);
        const int d = (tid & 63) * 8;
        const float4 b0 = *(const float4*)(bO + d);
        const float4 b1 = *(const float4*)(bO + d + 4);
        *(float4*)(outp + q * DD + d)     = b0;
        *(float4*)(outp + q * DD + d + 4) = b1;
        return;
    }

    const int pt = blk & 7;         // 8 p-tiles of 32 rows
    const int n  = (blk >> 3) & 7;  // head
    const int lane = tid & 63;
    const int wid  = tid >> 6;
    const int r15  = lane & 15;     // MFMA M/N index
    const int quad = lane >> 4;     // MFMA k-group / row-group
    const int p0 = pt * 32;

    const float* W;
    if (m == 0)      W = WK1  + n * DD * HH;
    else if (m == 1) W = WK2  + n * DD * HH;
    else if (m == 2) W = WQ   + n * DD * HH;
    else if (m == 3) W = WV12 + n * 2 * DD * HH;
    else             W = WV12 + n * 2 * DD * HH + DD * HH;

    // ---- stage x rows p0..p0+31 (f32 -> bf16, swizzled) ----------------------
    for (int it = 0; it < 8; ++it) {
        const int idx = tid + it * 256;   // chunk id 0..2047 (32 rows x 64)
        const int row = idx >> 6;
        const int c8  = idx & 63;
        const float4 xa = *(const float4*)(x + (p0 + row) * DD + c8 * 8);
        const float4 xb = *(const float4*)(x + (p0 + row) * DD + c8 * 8 + 4);
        bf16x8 v;
        v[0]=(__bf16)xa.x; v[1]=(__bf16)xa.y; v[2]=(__bf16)xa.z; v[3]=(__bf16)xa.w;
        v[4]=(__bf16)xb.x; v[5]=(__bf16)xb.y; v[6]=(__bf16)xb.z; v[7]=(__bf16)xb.w;
        *(bf16x8*)&xsh[row * DD + ((c8 ^ (row & 7)) << 3)] = v;
    }
    __syncthreads();

    // ---- MFMA: wave w -> h-tile w, both p-sub-tiles; K = 512 -----------------
    const int h0 = wid << 4;
    const int swz = r15 & 7;          // row swizzle key
    floatx4 C0 = {0.f,0.f,0.f,0.f}, C1 = {0.f,0.f,0.f,0.f};
    for (int kk = 0; kk < 16; ++kk) {
        const int c8 = (kk << 2) + quad;                 // 16B chunk of k-range
        const bf16x8 A0 = *(const bf16x8*)&xsh[ r15       * DD + ((c8 ^ swz) << 3)];
        const bf16x8 A1 = *(const bf16x8*)&xsh[(16 + r15) * DD + ((c8 ^ swz) << 3)];
        const float* Wp = W + (kk * 32 + quad * 8) * HH + h0 + r15;
        bf16x8 Bv;
        #pragma unroll
        for (int j = 0; j < 8; ++j) Bv[j] = (__bf16)Wp[j * HH];
        C0 = __builtin_amdgcn_mfma_f32_16x16x32_bf16(A0, Bv, C0, 0, 0, 0);
        C1 = __builtin_amdgcn_mfma_f32_16x16x32_bf16(A1, Bv, C1, 0, 0, 0);
    }

    // ---- epilogue: bias, scale, store (C: col=r15 -> h, row=quad*4+i -> p) ---
    float bv = 0.f;
    if (m == 0)      bv = bK1[n * HH + h0 + r15];
    else if (m == 1) bv = bK2[n * HH + h0 + r15];
    else if (m == 2) bv = bQ[n * HH + h0 + r15];

    if (m == 1) {
        const int h = h0 + r15;
        const int c8 = h >> 3;
        #pragma unroll
        for (int i = 0; i < 4; ++i) {
            int p = p0 + quad * 4 + i;
            K2bf[(n * SS + p) * HH + ((c8 ^ (p & 7)) << 3) + (h & 7)] =
                (__bf16)(C0[i] + bv);
            p += 16;
            K2bf[(n * SS + p) * HH + ((c8 ^ (p & 7)) << 3) + (h & 7)] =
                (__bf16)(C1[i] + bv);
        }
    } else if (m >= 3) {
        __bf16* outb = (m == 3) ? VAbf : VBbf;
        #pragma unroll
        for (int i = 0; i < 4; ++i) {
            const int p = p0 + quad * 4 + i;
            outb[(n * SS + p) * HH + h0 + r15]      = (__bf16)C0[i];
            outb[(n * SS + p + 16) * HH + h0 + r15] = (__bf16)C1[i];
        }
    } else {
        float* outb = (m == 0) ? K1b : Qb;
        const float scale = (m == 2) ? (1.0f / 64.0f) : 1.0f;  // fold 1/H into Q
        #pragma unroll
        for (int i = 0; i < 4; ++i) {
            const int p = p0 + quad * 4 + i;
            outb[(n * SS + p) * HH + h0 + r15]      = (C0[i] + bv) * scale;
            outb[(n * SS + p + 16) * HH + h0 + r15] = (C1[i] + bv) * scale;
        }
    }
}

// ---------------------------------------------------------------------------
// Kernel B: block = (n, q-pair {g, 255-g}), g in [0,128) -> 1024 blocks =
// exactly 4 blocks/CU co-resident (LDS ~38.5KB, VGPR<=128 via
// __launch_bounds__(256,4)) -> 50% occupancy ceiling vs 25% before.
// K2 staged as a straight 32KB bf16 copy (proj pre-swizzled); A-frags per
// (strip, q) from global f32 k1 * LDS qs; B-frags shared across the 2 q's.
// Marginals a_s (register+butterfly) and c_t (LDS atomic) per q; masked
// entries are exactly 0 in the reference (exp underflow) so excluding them is
// exact; q<2 rows fully masked -> preset uniform 1/256 (Z sums to exactly 1).
// z[q,n,:] = (sum_s a_s VA[s] + sum_t c_t VB[t]) * invZ + b_V12, then this
// block's out-contribution z . WO[n*64:(n+1)*64, :] is atomicAdd-ed into out
// (bias pre-written by proj; stream order + device-scope atomics = safe).
// ---------------------------------------------------------------------------
__global__ __launch_bounds__(256, 4) void attn_kernel(
    const float* __restrict__ K1b, const __bf16* __restrict__ K2bf,
    const float* __restrict__ Qb,  const __bf16* __restrict__ VAbf,
    const __bf16* __restrict__ VBbf, const float* __restrict__ bV12,
    const float* __restrict__ WO, float* __restrict__ outp)
{
    const int n = blockIdx.x & 7;            // %8: same head -> same XCD L2
    const int g = (int)(blockIdx.x >> 3);    // 0..127
    int qs2[2];
    qs2[0] = g; qs2[1] = 255 - g;
    const int qmax = qs2[1];                 // >= 128 always

    const int tid  = threadIdx.x;
    const int lane = tid & 63;
    const int wid  = tid >> 6;
    const int r15  = lane & 15;   // MFMA free-dim (t) index
    const int quad = lane >> 4;   // MFMA k-group / s-row group

    __shared__ __bf16 K2sh[SS * HH];   // 32 KB, already swizzled by proj
    __shared__ float qsh[2][HH];       // q rows; later reused for final z rows
    __shared__ float a_lds[2][SS];
    __shared__ float c_lds[2][SS];
    __shared__ float zred[2][4][HH];
    __shared__ float red[2][4];

    // ---- stage K2 (plain bf16 copy) + the 2 q rows ---------------------------
    {
        const __bf16* src = K2bf + (n << 8) * HH;
        for (int it = 0; it < 8; ++it) {
            const int idx = tid + it * 256;  // 2048 16B chunks
            *(bf16x8*)&K2sh[idx * 8] = *(const bf16x8*)&src[idx * 8];
        }
        if (tid < 32) {
            const int qi = tid >> 4, c = tid & 15;
            const float4 qv = *(const float4*)(Qb + ((n << 8) + qs2[qi]) * HH + c * 4);
            *(float4*)&qsh[qi][c * 4] = qv;
        }
        #pragma unroll
        for (int qi = 0; qi < 2; ++qi) {
            const float init = (qs2[qi] < 2) ? (1.0f / SS) : 0.f;
            a_lds[qi][tid] = init;
            c_lds[qi][tid] = init;
        }
    }
    __syncthreads();

    // ---- score strips --------------------------------------------------------
    #pragma unroll
    for (int j = 0; j < 4; ++j) {
        int strip;
        if (j == 0) strip = wid;
        else if (j == 1) strip = 7 - wid;
        else if (j == 2) strip = 8 + wid;
        else strip = 15 - wid;
        const int s0 = strip << 4;
        if (s0 + 2 > qmax) continue;

        // k1 fragment rows (shared across the 2 q's)
        const float* k1p = K1b + ((n << 8) + s0 + r15) * HH;
        const float4 ka = *(const float4*)(k1p + quad * 8);
        const float4 kb = *(const float4*)(k1p + quad * 8 + 4);
        const float4 kc = *(const float4*)(k1p + 32 + quad * 8);
        const float4 kd = *(const float4*)(k1p + 32 + quad * 8 + 4);

        bf16x8 a0q[2], a1q[2];
        #pragma unroll
        for (int qi = 0; qi < 2; ++qi) {
            const float4 qa = *(const float4*)&qsh[qi][quad * 8];
            const float4 qb_ = *(const float4*)&qsh[qi][quad * 8 + 4];
            const float4 qc = *(const float4*)&qsh[qi][32 + quad * 8];
            const float4 qd = *(const float4*)&qsh[qi][32 + quad * 8 + 4];
            a0q[qi][0] = (__bf16)(ka.x * qa.x); a0q[qi][1] = (__bf16)(ka.y * qa.y);
            a0q[qi][2] = (__bf16)(ka.z * qa.z); a0q[qi][3] = (__bf16)(ka.w * qa.w);
            a0q[qi][4] = (__bf16)(kb.x * qb_.x); a0q[qi][5] = (__bf16)(kb.y * qb_.y);
            a0q[qi][6] = (__bf16)(kb.z * qb_.z); a0q[qi][7] = (__bf16)(kb.w * qb_.w);
            a1q[qi][0] = (__bf16)(kc.x * qc.x); a1q[qi][1] = (__bf16)(kc.y * qc.y);
            a1q[qi][2] = (__bf16)(kc.z * qc.z); a1q[qi][3] = (__bf16)(kc.w * qc.w);
            a1q[qi][4] = (__bf16)(kd.x * qd.x); a1q[qi][5] = (__bf16)(kd.y * qd.y);
            a1q[qi][6] = (__bf16)(kd.z * qd.z); a1q[qi][7] = (__bf16)(kd.w * qd.w);
        }

        float rowAcc[2][4] = {};
        const int swz = r15 & 7;
        for (int t0 = s0; t0 < qmax; t0 += 16) {
            const __bf16* K2row = &K2sh[(t0 + r15) * HH];
            const bf16x8 b0 = *(const bf16x8*)&K2row[((quad    ) ^ swz) << 3];
            const bf16x8 b1 = *(const bf16x8*)&K2row[((quad + 4) ^ swz) << 3];
            #pragma unroll
            for (int qi = 0; qi < 2; ++qi) {
                const int qv = qs2[qi];
                if (t0 >= qv || s0 + 2 > qv) continue;   // wave-uniform skip
                floatx4 C = {0.f, 0.f, 0.f, 0.f};
                C = __builtin_amdgcn_mfma_f32_16x16x32_bf16(a0q[qi], b0, C, 0, 0, 0);
                C = __builtin_amdgcn_mfma_f32_16x16x32_bf16(a1q[qi], b1, C, 0, 0, 0);

                float e[4];
                if (t0 >= s0 + 16 && t0 + 16 <= qv) {    // interior: no masking
                    #pragma unroll
                    for (int i = 0; i < 4; ++i) e[i] = __expf(C[i]);
                } else {
                    const int t = t0 + r15;
                    #pragma unroll
                    for (int i = 0; i < 4; ++i) {
                        const int s = s0 + quad * 4 + i;
                        e[i] = (s < t && t < qv) ? __expf(C[i]) : 0.f;
                    }
                }
                #pragma unroll
                for (int i = 0; i < 4; ++i) rowAcc[qi][i] += e[i];

                // column (t) sums: lanes {r15, r15+16, r15+32, r15+48}
                float cs = (e[0] + e[1]) + (e[2] + e[3]);
                cs += __shfl_xor(cs, 16, 64);
                cs += __shfl_xor(cs, 32, 64);
                if (lane < 16) atomicAdd(&c_lds[qi][t0 + r15], cs);
            }
        }
        // row (s) sums: butterfly over the 16 column-lanes; strip-exclusive rows
        #pragma unroll
        for (int qi = 0; qi < 2; ++qi) {
            if (s0 + 2 > qs2[qi]) continue;
            #pragma unroll
            for (int i = 0; i < 4; ++i) {
                rowAcc[qi][i] += __shfl_xor(rowAcc[qi][i], 1, 64);
                rowAcc[qi][i] += __shfl_xor(rowAcc[qi][i], 2, 64);
                rowAcc[qi][i] += __shfl_xor(rowAcc[qi][i], 4, 64);
                rowAcc[qi][i] += __shfl_xor(rowAcc[qi][i], 8, 64);
            }
            if (r15 == 0) {
                #pragma unroll
                for (int i = 0; i < 4; ++i)
                    a_lds[qi][s0 + quad * 4 + i] = rowAcc[qi][i];
            }
        }
    }
    __syncthreads();

    // ---- Z per q (q<2 presets sum to exactly 1.0 -> invZ = 1) ---------------
    #pragma unroll
    for (int qi = 0; qi < 2; ++qi) {
        float v = a_lds[qi][tid];
        #pragma unroll
        for (int off = 32; off >= 1; off >>= 1) v += __shfl_xor(v, off, 64);
        if (lane == 0) red[qi][wid] = v;
    }
    __syncthreads();
    float invZ[2];
    #pragma unroll
    for (int qi = 0; qi < 2; ++qi)
        invZ[qi] = 1.0f / (red[qi][0] + red[qi][1] + red[qi][2] + red[qi][3]);

    // ---- z = (sum_s a_s VA[s] + sum_t c_t VB[t]) * invZ + b_V12 --------------
    {
        const int h = lane;
        const int gg = wid;                 // s-range [gg*64, gg*64+64)
        const __bf16* VAp = VAbf + ((n << 8) + (gg << 6)) * HH + h;
        const __bf16* VBp = VBbf + ((n << 8) + (gg << 6)) * HH + h;
        float acc[2] = {0.f, 0.f};
        for (int i = 0; i < 64; ++i) {
            const float va = (float)VAp[i * HH];
            const float vb = (float)VBp[i * HH];
            const int si = (gg << 6) + i;
            #pragma unroll
            for (int qi = 0; qi < 2; ++qi)
                acc[qi] = fmaf(a_lds[qi][si], va,
                          fmaf(c_lds[qi][si], vb, acc[qi]));
        }
        #pragma unroll
        for (int qi = 0; qi < 2; ++qi) zred[qi][gg][h] = acc[qi];
    }
    __syncthreads();
    if (tid < 128) {    // final z rows into qsh (reused; q-row reads are done)
        const int qi = tid >> 6;
        const int h = tid & 63;
        qsh[qi][h] = (zred[qi][0][h] + zred[qi][1][h] +
                      zred[qi][2][h] + zred[qi][3][h]) * invZ[qi]
                   + bV12[n * HH + h];
    }
    __syncthreads();

    // ---- fused epilogue GEMM: out[q,:] += z[q, n-slice] . WO[n*64:, :] -------
    // wave w serves d-stripe [w*128, w*128+128) for BOTH q's (WO read amortized)
    {
        const int d0 = (wid << 7) + lane * 2;
        const float* WOp = WO + (n * HH) * DD;
        float2 acc0 = {0.f, 0.f}, acc1 = {0.f, 0.f};
        for (int h = 0; h < HH; ++h) {
            const float2 w = *(const float2*)(WOp + h * DD + d0);
            const float z0 = qsh[0][h];            // LDS broadcast
            const float z1 = qsh[1][h];
            acc0.x = fmaf(z0, w.x, acc0.x); acc0.y = fmaf(z0, w.y, acc0.y);
            acc1.x = fmaf(z1, w.x, acc1.x); acc1.y = fmaf(z1, w.y, acc1.y);
        }
        float* op0 = outp + qs2[0] * DD + d0;
        float* op1 = outp + qs2[1] * DD + d0;
        atomicAdd(op0,     acc0.x);
        atomicAdd(op0 + 1, acc0.y);
        atomicAdd(op1,     acc1.x);
        atomicAdd(op1 + 1, acc1.y);
    }
}

// ---------------------------------------------------------------------------
extern "C" void kernel_launch(void* const* d_in, const int* in_sizes, int n_in,
                              void* d_out, int out_size, void* d_ws, size_t ws_size,
                              hipStream_t stream)
{
    const float* x    = (const float*)d_in[0];
    const float* WK1  = (const float*)d_in[1];
    const float* WK2  = (const float*)d_in[2];
    const float* WQ   = (const float*)d_in[3];
    const float* WV12 = (const float*)d_in[4];
    const float* WO   = (const float*)d_in[5];
    const float* bK1  = (const float*)d_in[6];
    const float* bK2  = (const float*)d_in[7];
    const float* bQ   = (const float*)d_in[8];
    const float* bV12 = (const float*)d_in[9];
    const float* bO   = (const float*)d_in[10];
    float* out = (float*)d_out;

    float* ws  = (float*)d_ws;
    const int T = NN * SS * HH;  // 131072 elements per projected tensor
    float*  K1b  = ws + 0 * T;
    float*  Qb   = ws + 1 * T;
    __bf16* b16  = (__bf16*)(ws + 2 * T);
    __bf16* K2bf = b16 + 0 * T;   // pre-swizzled
    __bf16* VAbf = b16 + 1 * T;
    __bf16* VBbf = b16 + 2 * T;

    proj_kernel<<<384, 256, 0, stream>>>(x, WK1, WK2, WQ, WV12,
                                         bK1, bK2, bQ, bO,
                                         K1b, Qb, K2bf, VAbf, VBbf, out);
    attn_kernel<<<1024, 256, 0, stream>>>(K1b, K2bf, Qb, VAbf, VBbf, bV12,
                                          WO, out);
}